// Round 1
// baseline (7624.725 us; speedup 1.0000x reference)
//
#include <hip/hip_runtime.h>
#include <math.h>

namespace {

constexpr int TTc = 256, NHEAD = 4;
constexpr int BTc = 16384;           // 64*256
constexpr int HBT = 8192;            // 32*256
constexpr long HHf = 4194304;        // 8192*512

// workspace offsets (floats)
constexpr long F_H     = 0;          // h / x_emb (8388608)
constexpr long F_LN    = 8388608;    // ln / o buffer; later att_full (4x491520)
constexpr long F_QKV   = 16777216;   // qkv (25165824); later augs (4x4194304)
constexpr long F_SC    = 41943040;   // scores chunk (4194304)
constexpr long F_ATT   = F_LN;
constexpr long F_AUG   = F_QKV;
constexpr long F_MU    = 33554432;   // N_aug_mu ; later A_aug_new
constexpr long F_VAR   = 37748736;   // N_aug_var ; later A_Naug_m
constexpr long F_NNEW  = 41943040;   // N_aug_new
constexpr long F_NAM   = 46137344;   // N_Aaug_m
constexpr long F_SMALL = 50331648;
constexpr long O_ANC  = F_SMALL;
constexpr long O_POS  = F_SMALL + 16384;
constexpr long O_NEG  = F_SMALL + 32768;
constexpr long O_ANEW = F_SMALL + 49152;
constexpr long O_NNEG = F_SMALL + 65536;
constexpr long O_IDX  = F_SMALL + 81920;   // 3 * 544 ints
constexpr long O_ACC  = F_SMALL + 83552;   // 4 floats: kl, trip, cos, dist

// output offsets (floats)
constexpr long OO_AATT  = 3;
constexpr long OO_NATT  = 3 + 8192;
constexpr long OO_ANATT = 3 + 16384;
constexpr long OO_NAATT = 3 + 24576;
constexpr long OO_COS   = 32771;
constexpr long OO_XOUT  = 32772;
constexpr long OO_VFEAT = 32772L + 16777216L;

struct GP {
  const float* A; const float* B; const float* bias; float* C;
  int M, N, K, lda, ldb, ldc;
  long sAb, sAh, sBb, sBh, sCb, sCh;
  int Hdiv; float scale;
};

__device__ inline float bred_sum(float v, float* sm, int tid) {
  sm[tid] = v; __syncthreads();
  for (int s = 128; s > 0; s >>= 1) { if (tid < s) sm[tid] += sm[tid + s]; __syncthreads(); }
  float r = sm[0]; __syncthreads();
  return r;
}
__device__ inline float bred_max(float v, float* sm, int tid) {
  sm[tid] = v; __syncthreads();
  for (int s = 128; s > 0; s >>= 1) { if (tid < s) sm[tid] = fmaxf(sm[tid], sm[tid + s]); __syncthreads(); }
  float r = sm[0]; __syncthreads();
  return r;
}

// ---------------- generic tiled GEMM ----------------
// C = epi(scale * A@B + bias) [+ C_old if ACC]; optional two-level batch (b,h)
template<int EPI, bool TRANSB, bool ACC>
__global__ __launch_bounds__(256) void gemm_k(GP p) {
  int bz = blockIdx.z;
  int bb = bz / p.Hdiv, hh = bz % p.Hdiv;
  const float* A = p.A + (long)bb * p.sAb + (long)hh * p.sAh;
  const float* Bm = p.B + (long)bb * p.sBb + (long)hh * p.sBh;
  float* C = p.C + (long)bb * p.sCb + (long)hh * p.sCh;
  int m0 = blockIdx.x * 64, n0 = blockIdx.y * 64;
  __shared__ float As[64][17];
  __shared__ float Bs[16][65];
  int tid = threadIdx.x;
  int tx = tid & 15, ty = tid >> 4;
  float acc[4][4] = {};
  for (int k0 = 0; k0 < p.K; k0 += 16) {
    for (int e = tid; e < 64 * 16; e += 256) {
      int r = e >> 4, c = e & 15;
      int m = m0 + r, kk = k0 + c;
      As[r][c] = (m < p.M && kk < p.K) ? A[(long)m * p.lda + kk] : 0.f;
    }
    if (TRANSB) {
      for (int e = tid; e < 16 * 64; e += 256) {
        int n = e >> 4, c = e & 15;
        int nn = n0 + n, kk = k0 + c;
        Bs[c][n] = (nn < p.N && kk < p.K) ? Bm[(long)nn * p.ldb + kk] : 0.f;
      }
    } else {
      for (int e = tid; e < 16 * 64; e += 256) {
        int c = e >> 6, n = e & 63;
        int kk = k0 + c, nn = n0 + n;
        Bs[c][n] = (kk < p.K && nn < p.N) ? Bm[(long)kk * p.ldb + nn] : 0.f;
      }
    }
    __syncthreads();
#pragma unroll
    for (int c = 0; c < 16; ++c) {
      float a[4], b[4];
#pragma unroll
      for (int i = 0; i < 4; i++) a[i] = As[ty * 4 + i][c];
#pragma unroll
      for (int j = 0; j < 4; j++) b[j] = Bs[c][tx * 4 + j];
#pragma unroll
      for (int i = 0; i < 4; i++)
#pragma unroll
        for (int j = 0; j < 4; j++) acc[i][j] += a[i] * b[j];
    }
    __syncthreads();
  }
  for (int i = 0; i < 4; i++) {
    int m = m0 + ty * 4 + i;
    if (m >= p.M) break;
    for (int j = 0; j < 4; j++) {
      int n = n0 + tx * 4 + j;
      if (n >= p.N) continue;
      float v = acc[i][j] * p.scale;
      if (p.bias) v += p.bias[n];
      if (EPI == 1) v = 0.5f * v * (1.f + erff(v * 0.70710678118654752f));
      if (EPI == 2) v = 1.f / (1.f + expf(-v));
      long ci = (long)m * p.ldc + n;
      if (ACC) v += C[ci];
      C[ci] = v;
    }
  }
}

// ---------------- conv1d k=3 pad=1 (implicit im2col GEMM) ----------------
__global__ __launch_bounds__(256) void conv_k(const float* __restrict__ x,
    const float* __restrict__ w, const float* __restrict__ bias, float* __restrict__ out) {
  int m0 = blockIdx.x * 64;     // over 16384 rows (b,t)
  int n0 = blockIdx.y * 64;     // over 512 d
  int b = m0 / 256, tb = m0 % 256;
  __shared__ float As[64][17];
  __shared__ float Bs[16][65];
  int tid = threadIdx.x, tx = tid & 15, ty = tid >> 4;
  float acc[4][4] = {};
  for (int c0 = 0; c0 < 3072; c0 += 16) {
    for (int e = tid; e < 64 * 16; e += 256) {
      int r = e >> 4, c = e & 15;
      int cc = c0 + c;
      int i = cc / 3, k = cc - 3 * i;
      int t2 = tb + r + k - 1;
      As[r][c] = (t2 >= 0 && t2 < 256) ? x[((long)(b * 256 + t2)) * 1024 + i] : 0.f;
    }
    for (int e = tid; e < 16 * 64; e += 256) {
      int n = e >> 4, c = e & 15;
      Bs[c][n] = w[(long)(n0 + n) * 3072 + c0 + c];
    }
    __syncthreads();
#pragma unroll
    for (int c = 0; c < 16; ++c) {
      float a[4], bq[4];
#pragma unroll
      for (int i = 0; i < 4; i++) a[i] = As[ty * 4 + i][c];
#pragma unroll
      for (int j = 0; j < 4; j++) bq[j] = Bs[c][tx * 4 + j];
#pragma unroll
      for (int i = 0; i < 4; i++)
#pragma unroll
        for (int j = 0; j < 4; j++) acc[i][j] += a[i] * bq[j];
    }
    __syncthreads();
  }
  for (int i = 0; i < 4; i++)
    for (int j = 0; j < 4; j++) {
      int m = m0 + ty * 4 + i, n = n0 + tx * 4 + j;
      float v = acc[i][j] + bias[n];
      out[(long)m * 512 + n] = v > 0.f ? v : 0.f;
    }
}

// ---------------- layernorm (rows of 512) ----------------
__global__ __launch_bounds__(256) void ln_k(const float* __restrict__ in,
    const float* __restrict__ g, const float* __restrict__ b, float* __restrict__ out) {
  long row = blockIdx.x;
  const float* r = in + row * 512;
  int tid = threadIdx.x;
  __shared__ float sm[256];
  float x0 = r[tid], x1 = r[tid + 256];
  float mean = bred_sum(x0 + x1, sm, tid) * (1.f / 512.f);
  float d0 = x0 - mean, d1 = x1 - mean;
  float var = bred_sum(d0 * d0 + d1 * d1, sm, tid) * (1.f / 512.f);
  float inv = rsqrtf(var + 1e-5f);
  out[row * 512 + tid]       = d0 * inv * g[tid] + b[tid];
  out[row * 512 + tid + 256] = d1 * inv * g[tid + 256] + b[tid + 256];
}

// ---------------- softmax (rows of 256) ----------------
__global__ __launch_bounds__(256) void softmax_k(float* __restrict__ s) {
  long row = blockIdx.x;
  float* r = s + row * 256;
  int tid = threadIdx.x;
  __shared__ float sm[256];
  float v = r[tid];
  float mx = bred_max(v, sm, tid);
  float e = expf(v - mx);
  float sum = bred_sum(e, sm, tid);
  r[tid] = e / sum;
}

// ---------------- top-4 mean over 60 ----------------
__global__ __launch_bounds__(256) void top4_k(const float* __restrict__ att, float* __restrict__ out) {
  int i = blockIdx.x * 256 + threadIdx.x;
  if (i >= HBT) return;
  const float* a = att + (long)i * 60;
  float t0 = -1e30f, t1 = -1e30f, t2 = -1e30f, t3 = -1e30f;
  for (int k = 0; k < 60; k++) {
    float v = a[k];
    if (v > t0)      { t3 = t2; t2 = t1; t1 = t0; t0 = v; }
    else if (v > t1) { t3 = t2; t2 = t1; t1 = v; }
    else if (v > t2) { t3 = t2; t2 = v; }
    else if (v > t3) { t3 = v; }
  }
  out[i] = (t0 + t1 + t2 + t3) * 0.25f;
}

// ---------------- top-17 indices over 256 (per batch row) ----------------
__global__ void topk17_k(const float* __restrict__ tatt, int* __restrict__ idx) {
  int b = threadIdx.x;
  if (b >= 32) return;
  const float* r = tatt + (long)b * 256;
  unsigned long long used[4] = {0, 0, 0, 0};
  for (int s = 0; s < 17; s++) {
    float best = -1e30f; int bi = 0;
    for (int t = 0; t < 256; t++) {
      if ((used[t >> 6] >> (t & 63)) & 1ull) continue;
      float v = r[t];
      if (v > best) { best = v; bi = t; }
    }
    used[bi >> 6] |= 1ull << (bi & 63);
    idx[b * 17 + s] = bi;
  }
}

// ---------------- gather 17 rows, mean -> (32,512) ----------------
__global__ __launch_bounds__(256) void gmean_k(const float* __restrict__ feats,
    const int* __restrict__ idx, float* __restrict__ out) {
  int b = blockIdx.x, tid = threadIdx.x;
  float s0 = 0.f, s1 = 0.f;
  for (int j = 0; j < 17; j++) {
    int t = idx[b * 17 + j];
    const float* r = feats + ((long)b * 256 + t) * 512;
    s0 += r[tid]; s1 += r[tid + 256];
  }
  out[(long)b * 512 + tid]       = s0 * (1.f / 17.f);
  out[(long)b * 512 + tid + 256] = s1 * (1.f / 17.f);
}

// ---------------- VAE reparam + KL partial ----------------
__global__ __launch_bounds__(256) void vae_k(const float* __restrict__ mu,
    const float* __restrict__ var, const float* __restrict__ eps,
    float* __restrict__ nnew, float* __restrict__ accum) {
  long i = (long)blockIdx.x * 256 + threadIdx.x;
  float m = mu[i], v = var[i], ev = expf(v);
  nnew[i] = m + eps[i] * sqrtf(ev);
  float kle = 1.f + v - m * m - ev;
  __shared__ float sm[256];
  float s = bred_sum(kle, sm, threadIdx.x);
  if (threadIdx.x == 0) atomicAdd(accum + 0, s);
}

// ---------------- triplet + cos ----------------
__global__ __launch_bounds__(256) void tripcos_k(const float* __restrict__ anc,
    const float* __restrict__ pos, const float* __restrict__ neg, float* __restrict__ accum) {
  int b = blockIdx.x, tid = threadIdx.x;
  const float *a = anc + (long)b * 512, *p = pos + (long)b * 512, *n = neg + (long)b * 512;
  float a0 = a[tid], a1 = a[tid + 256], p0 = p[tid], p1 = p[tid + 256], n0 = n[tid], n1 = n[tid + 256];
  __shared__ float sm[256];
  float sa  = bred_sum(a0 * a0 + a1 * a1, sm, tid);
  float sp  = bred_sum(p0 * p0 + p1 * p1, sm, tid);
  float sn  = bred_sum(n0 * n0 + n1 * n1, sm, tid);
  float dot = bred_sum(a0 * n0 + a1 * n1, sm, tid);
  float na = sqrtf(sa), np_ = sqrtf(sp), nn = sqrtf(sn);
  float ina = 1.f / na, inp = 1.f / np_, inn = 1.f / nn;
  float d0 = a0 * ina - p0 * inp + 1e-6f, d1 = a1 * ina - p1 * inp + 1e-6f;
  float e0 = a0 * ina - n0 * inn + 1e-6f, e1 = a1 * ina - n1 * inn + 1e-6f;
  float dp2 = bred_sum(d0 * d0 + d1 * d1, sm, tid);
  float dn2 = bred_sum(e0 * e0 + e1 * e1, sm, tid);
  if (tid == 0) {
    float dp = sqrtf(dp2), dn = sqrtf(dn2);
    float t = dp - dn + 1.f;
    atomicAdd(accum + 1, t > 0.f ? t : 0.f);
    float c = 1.f - dot / (fmaxf(na, 1e-6f) * fmaxf(nn, 1e-6f));
    atomicAdd(accum + 2, c);
  }
}

// ---------------- distance ----------------
__global__ __launch_bounds__(256) void dist_k(const float* __restrict__ anew,
    const float* __restrict__ nneg, float* __restrict__ accum) {
  int b = blockIdx.x, tid = threadIdx.x;
  const float *a = anew + (long)b * 512, *n = nneg + (long)b * 512;
  float a0 = a[tid], a1 = a[tid + 256], n0 = n[tid], n1 = n[tid + 256];
  __shared__ float sm[256];
  float sa = bred_sum(a0 * a0 + a1 * a1, sm, tid);
  float sn = bred_sum(n0 * n0 + n1 * n1, sm, tid);
  if (tid == 0) {
    float v = 100.f - sqrtf(sn) + sqrtf(sa);
    atomicAdd(accum + 3, v > 0.f ? v : 0.f);
  }
}

// ---------------- x_out assembly ----------------
__global__ __launch_bounds__(256) void xout_k(const float* __restrict__ emb,
    const float* __restrict__ nnew, const float* __restrict__ anm,
    const float* __restrict__ anew, const float* __restrict__ nam,
    float* __restrict__ xout) {
  long i = (long)blockIdx.x * 256 + threadIdx.x;   // over 8388608
  long row = i >> 9;
  int d = (int)(i & 511);
  long o = row * 1024 + d;
  xout[o] = emb[i];
  float v;
  if (i < HHf) v = nnew[i] + anm[i];
  else         v = anew[i - HHf] + nam[i - HHf];
  xout[o + 512] = v;
}

// ---------------- v_feat transpose ----------------
__global__ __launch_bounds__(256) void vfeat_k(const float* __restrict__ emb, float* __restrict__ vf) {
  __shared__ float tile[32][33];
  int b = blockIdx.z;
  int t0 = blockIdx.x * 32, d0 = blockIdx.y * 32;
  int tx = threadIdx.x & 31, ty = threadIdx.x >> 5;  // ty 0..7
  for (int r = 0; r < 32; r += 8)
    tile[ty + r][tx] = emb[((long)b * 256 + t0 + ty + r) * 512 + d0 + tx];
  __syncthreads();
  for (int r = 0; r < 32; r += 8)
    vf[((long)b * 512 + d0 + ty + r) * 256 + t0 + tx] = tile[tx][ty + r];
}

__global__ void init_k(float* accum) {
  accum[0] = 0.f; accum[1] = 0.f; accum[2] = 0.f; accum[3] = 0.f;
}

__global__ void fin_k(const float* __restrict__ accum, float* __restrict__ out) {
  out[0] = accum[1] * (1.f / 32.f);            // triplet
  out[1] = -0.5f * accum[0] * (1.f / 16384.f); // kl
  out[2] = accum[3] * (1.f / 32.f);            // distance
  out[OO_COS] = accum[2] * (1.f / 32.f);       // cos
}

static inline GP mkgp(const float* A, const float* B, const float* bias, float* C,
                      int M, int N, int K, int lda, int ldb, int ldc,
                      long sAb, long sAh, long sBb, long sBh, long sCb, long sCh,
                      int Hdiv, float scale) {
  GP p; p.A = A; p.B = B; p.bias = bias; p.C = C;
  p.M = M; p.N = N; p.K = K; p.lda = lda; p.ldb = ldb; p.ldc = ldc;
  p.sAb = sAb; p.sAh = sAh; p.sBb = sBb; p.sBh = sBh; p.sCb = sCb; p.sCh = sCh;
  p.Hdiv = Hdiv; p.scale = scale;
  return p;
}

} // namespace

extern "C" void kernel_launch(void* const* d_in, const int* in_sizes, int n_in,
                              void* d_out, int out_size, void* d_ws, size_t ws_size,
                              hipStream_t stream) {
  const float* x      = (const float*)d_in[0];
  const float* epsi   = (const float*)d_in[1];
  const float* conv_w = (const float*)d_in[2];
  const float* conv_b = (const float*)d_in[3];
  const float* ln1_g  = (const float*)d_in[4];
  const float* ln1_b  = (const float*)d_in[5];
  const float* qkv_w  = (const float*)d_in[6];
  const float* out_w  = (const float*)d_in[7];
  const float* out_b  = (const float*)d_in[8];
  const float* ln2_g  = (const float*)d_in[9];
  const float* ln2_b  = (const float*)d_in[10];
  const float* ff1_w  = (const float*)d_in[11];
  const float* ff1_b  = (const float*)d_in[12];
  const float* ff2_w  = (const float*)d_in[13];
  const float* ff2_b  = (const float*)d_in[14];
  const float* a_mem  = (const float*)d_in[15];
  const float* n_mem  = (const float*)d_in[16];
  const float* mu_w   = (const float*)d_in[17];
  const float* mu_b   = (const float*)d_in[18];
  const float* var_w  = (const float*)d_in[19];
  const float* var_b  = (const float*)d_in[20];
  float* out = (float*)d_out;
  float* ws  = (float*)d_ws;

  const float ATTSCALE = 0.08838834764831845f;   // 128^-0.5
  const float SIGSCALE = 0.04419417382415922f;   // 512^-0.5

  // 1. conv + relu -> h
  conv_k<<<dim3(256, 8), 256, 0, stream>>>(x, conv_w, conv_b, ws + F_H);

  // 2. transformer layers
  for (int i = 0; i < 2; i++) {
    ln_k<<<16384, 256, 0, stream>>>(ws + F_H, ln1_g + i * 512, ln1_b + i * 512, ws + F_LN);
    {
      GP p = mkgp(ws + F_LN, qkv_w + (long)i * 512 * 1536, nullptr, ws + F_QKV,
                  BTc, 1536, 512, 512, 1536, 1536, 0, 0, 0, 0, 0, 0, 1, 1.f);
      gemm_k<0, false, false><<<dim3(256, 24, 1), 256, 0, stream>>>(p);
    }
    for (int c = 0; c < 4; c++) {
      long qoff = (long)c * 16 * TTc * 1536;
      {
        GP p = mkgp(ws + F_QKV + qoff, ws + F_QKV + qoff + 512, nullptr, ws + F_SC,
                    256, 256, 128, 1536, 1536, 256,
                    393216, 128, 393216, 128, 262144, 65536, NHEAD, ATTSCALE);
        gemm_k<0, true, false><<<dim3(4, 4, 64), 256, 0, stream>>>(p);
      }
      softmax_k<<<16384, 256, 0, stream>>>(ws + F_SC);
      {
        GP p = mkgp(ws + F_SC, ws + F_QKV + qoff + 1024, nullptr,
                    ws + F_LN + (long)c * 16 * TTc * 512,
                    256, 128, 256, 256, 1536, 512,
                    262144, 65536, 393216, 128, 131072, 128, NHEAD, 1.f);
        gemm_k<0, false, false><<<dim3(4, 2, 64), 256, 0, stream>>>(p);
      }
    }
    {
      GP p = mkgp(ws + F_LN, out_w + (long)i * 262144, out_b + i * 512, ws + F_H,
                  BTc, 512, 512, 512, 512, 512, 0, 0, 0, 0, 0, 0, 1, 1.f);
      gemm_k<0, false, true><<<dim3(256, 8, 1), 256, 0, stream>>>(p);
    }
    ln_k<<<16384, 256, 0, stream>>>(ws + F_H, ln2_g + i * 512, ln2_b + i * 512, ws + F_LN);
    {
      GP p = mkgp(ws + F_LN, ff1_w + (long)i * 262144, ff1_b + i * 512, ws + F_QKV,
                  BTc, 512, 512, 512, 512, 512, 0, 0, 0, 0, 0, 0, 1, 1.f);
      gemm_k<1, false, false><<<dim3(256, 8, 1), 256, 0, stream>>>(p);
    }
    {
      GP p = mkgp(ws + F_QKV, ff2_w + (long)i * 262144, ff2_b + i * 512, ws + F_H,
                  BTc, 512, 512, 512, 512, 512, 0, 0, 0, 0, 0, 0, 1, 1.f);
      gemm_k<0, false, true><<<dim3(256, 8, 1), 256, 0, stream>>>(p);
    }
  }

  const float* Nx = ws + F_H;
  const float* Ax = ws + F_H + HHf;
  float* attA  = ws + F_ATT;
  float* attNA = ws + F_ATT + 491520;
  float* attAN = ws + F_ATT + 983040;
  float* attN  = ws + F_ATT + 1474560;

  // 3. memory sigmoid attentions (full 60-col att matrices)
  {
    GP p = mkgp(Ax, a_mem, nullptr, attA, HBT, 60, 512, 512, 512, 60, 0,0,0,0,0,0, 1, SIGSCALE);
    gemm_k<2, true, false><<<dim3(128, 1, 1), 256, 0, stream>>>(p);
    p = mkgp(Ax, n_mem, nullptr, attNA, HBT, 60, 512, 512, 512, 60, 0,0,0,0,0,0, 1, SIGSCALE);
    gemm_k<2, true, false><<<dim3(128, 1, 1), 256, 0, stream>>>(p);
    p = mkgp(Nx, a_mem, nullptr, attAN, HBT, 60, 512, 512, 512, 60, 0,0,0,0,0,0, 1, SIGSCALE);
    gemm_k<2, true, false><<<dim3(128, 1, 1), 256, 0, stream>>>(p);
    p = mkgp(Nx, n_mem, nullptr, attN, HBT, 60, 512, 512, 512, 60, 0,0,0,0,0,0, 1, SIGSCALE);
    gemm_k<2, true, false><<<dim3(128, 1, 1), 256, 0, stream>>>(p);
  }

  // 4. temporal (top-4 mean) atts -> outputs
  top4_k<<<32, 256, 0, stream>>>(attA,  out + OO_AATT);
  top4_k<<<32, 256, 0, stream>>>(attN,  out + OO_NATT);
  top4_k<<<32, 256, 0, stream>>>(attAN, out + OO_ANATT);
  top4_k<<<32, 256, 0, stream>>>(attNA, out + OO_NAATT);

  // 5. augs = att @ mem
  {
    GP p = mkgp(attA, a_mem, nullptr, ws + F_AUG, HBT, 512, 60, 60, 512, 512, 0,0,0,0,0,0, 1, 1.f);
    gemm_k<0, false, false><<<dim3(128, 8, 1), 256, 0, stream>>>(p);           // A_aug
    p = mkgp(attN, n_mem, nullptr, ws + F_AUG + HHf, HBT, 512, 60, 60, 512, 512, 0,0,0,0,0,0, 1, 1.f);
    gemm_k<0, false, false><<<dim3(128, 8, 1), 256, 0, stream>>>(p);           // N_aug
    p = mkgp(attAN, a_mem, nullptr, ws + F_AUG + 2 * HHf, HBT, 512, 60, 60, 512, 512, 0,0,0,0,0,0, 1, 1.f);
    gemm_k<0, false, false><<<dim3(128, 8, 1), 256, 0, stream>>>(p);           // A_Naug
    p = mkgp(attNA, n_mem, nullptr, ws + F_AUG + 3 * HHf, HBT, 512, 60, 60, 512, 512, 0,0,0,0,0,0, 1, 1.f);
    gemm_k<0, false, false><<<dim3(128, 8, 1), 256, 0, stream>>>(p);           // N_Aaug
  }

  float* accum = ws + O_ACC;
  int* idxA = (int*)(ws + O_IDX);
  int* idxN = idxA + 544;
  int* idxP = idxN + 544;
  init_k<<<1, 1, 0, stream>>>(accum);

  // 6. top-17 indices
  topk17_k<<<1, 32, 0, stream>>>(out + OO_AATT,  idxA);
  topk17_k<<<1, 32, 0, stream>>>(out + OO_NATT,  idxN);
  topk17_k<<<1, 32, 0, stream>>>(out + OO_ANATT, idxP);

  // 7. gather means
  gmean_k<<<32, 256, 0, stream>>>(Ax, idxA, ws + O_NEG);   // negative_ax
  gmean_k<<<32, 256, 0, stream>>>(Nx, idxN, ws + O_ANC);   // anchor_nx
  gmean_k<<<32, 256, 0, stream>>>(Ax, idxP, ws + O_POS);   // positive_nx

  // 8. triplet + cos
  tripcos_k<<<32, 256, 0, stream>>>(ws + O_ANC, ws + O_POS, ws + O_NEG, accum);

  // 9. mu/var projections of N_aug; VAE reparam + KL
  {
    GP p = mkgp(ws + F_AUG + HHf, mu_w, mu_b, ws + F_MU, HBT, 512, 512, 512, 512, 512, 0,0,0,0,0,0, 1, 1.f);
    gemm_k<0, false, false><<<dim3(128, 8, 1), 256, 0, stream>>>(p);
    p = mkgp(ws + F_AUG + HHf, var_w, var_b, ws + F_VAR, HBT, 512, 512, 512, 512, 512, 0,0,0,0,0,0, 1, 1.f);
    gemm_k<0, false, false><<<dim3(128, 8, 1), 256, 0, stream>>>(p);
  }
  vae_k<<<16384, 256, 0, stream>>>(ws + F_MU, ws + F_VAR, epsi, ws + F_NNEW, accum);

  // 10. remaining mu-projections (reuse F_MU / F_VAR)
  {
    GP p = mkgp(ws + F_AUG, mu_w, mu_b, ws + F_MU, HBT, 512, 512, 512, 512, 512, 0,0,0,0,0,0, 1, 1.f);
    gemm_k<0, false, false><<<dim3(128, 8, 1), 256, 0, stream>>>(p);           // A_aug_new
    p = mkgp(ws + F_AUG + 2 * HHf, mu_w, mu_b, ws + F_VAR, HBT, 512, 512, 512, 512, 512, 0,0,0,0,0,0, 1, 1.f);
    gemm_k<0, false, false><<<dim3(128, 8, 1), 256, 0, stream>>>(p);           // A_Naug_m
    p = mkgp(ws + F_AUG + 3 * HHf, mu_w, mu_b, ws + F_NAM, HBT, 512, 512, 512, 512, 512, 0,0,0,0,0,0, 1, 1.f);
    gemm_k<0, false, false><<<dim3(128, 8, 1), 256, 0, stream>>>(p);           // N_Aaug_m
  }

  // 11. gathered-mean of new features; distance
  gmean_k<<<32, 256, 0, stream>>>(ws + F_NNEW, idxN, ws + O_ANEW);  // anchor_nx_new
  gmean_k<<<32, 256, 0, stream>>>(ws + F_MU,   idxA, ws + O_NNEG);  // negative_ax_new
  dist_k<<<32, 256, 0, stream>>>(ws + O_ANEW, ws + O_NNEG, accum);

  // 12. x_out assembly + v_feat transpose + scalars
  xout_k<<<32768, 256, 0, stream>>>(ws + F_H, ws + F_NNEW, ws + F_VAR, ws + F_MU, ws + F_NAM,
                                    out + OO_XOUT);
  vfeat_k<<<dim3(8, 16, 64), 256, 0, stream>>>(ws + F_H, out + OO_VFEAT);
  fin_k<<<1, 1, 0, stream>>>(accum, out);
}

// Round 2
// 3090.268 us; speedup vs baseline: 2.4673x; 2.4673x over previous
//
#include <hip/hip_runtime.h>
#include <math.h>

namespace {

typedef unsigned short u16;
typedef __attribute__((ext_vector_type(8))) short s8v;
typedef __attribute__((ext_vector_type(8))) unsigned short u16x8;
typedef __attribute__((ext_vector_type(4))) float f32x4;
typedef __attribute__((ext_vector_type(4))) unsigned int u32x4;

constexpr int HBT = 8192;            // 32*256
constexpr long HHf = 4194304;        // 8192*512

// ---- workspace offsets (float units) ----
constexpr long F_H    = 0;           // h / x_emb fp32 (8388608)
constexpr long F_LNB  = 8388608;     // ln / o / hbf bf16 (8388608 u16 = 4194304 fl)
constexpr long F_QKV  = 12582912;    // qkv bf16 (25165824 u16 = 12582912 fl); ff1 out reuses
constexpr long F_VT   = 25165824;    // v^T bf16 (8388608 u16 = 4194304 fl)
constexpr long F_SC   = 29360128;    // scores fp32 (16777216)  [dies before F_MU..F_NAM live]
// phase M (QKV/VT/SC regions dead):
constexpr long F_ATT  = 12582912;    // 4 x 491520 fp32
constexpr long F_AUG  = 14548992;    // 4 x 4194304 u16 = 8388608 fl
constexpr long F_MU   = 22937600;    // fp32 4194304
constexpr long F_VAR  = 27131904;
constexpr long F_NNEW = 31326208;
constexpr long F_NAM  = 35520512;
// transposed weights (bf16), live whole launch:
constexpr long W_QKV  = 46137344;    // 2 x 786432 u16
constexpr long W_OUT  = 46923776;    // 2 x 262144 u16
constexpr long W_FF1  = 47185920;
constexpr long W_FF2  = 47448064;
constexpr long W_MU   = 47710208;    // 262144 u16
constexpr long W_VAR  = 47841280;
constexpr long W_CONV = 47972352;    // 1572864 u16
constexpr long W_AMT  = 48758784;    // 32768 u16 (512x64 padded)
constexpr long W_NMT  = 48775168;
constexpr long O_ANC  = 48791552;
constexpr long O_POS  = O_ANC + 16384;
constexpr long O_NEG  = O_POS + 16384;
constexpr long O_ANEW = O_NEG + 16384;
constexpr long O_NNEG = O_ANEW + 16384;
constexpr long O_IDX  = O_NNEG + 16384;   // 3*544 ints
constexpr long O_ACC  = O_IDX + 1632;     // 4 floats

// ---- output offsets ----
constexpr long OO_AATT  = 3;
constexpr long OO_NATT  = 3 + 8192;
constexpr long OO_ANATT = 3 + 16384;
constexpr long OO_NAATT = 3 + 24576;
constexpr long OO_COS   = 32771;
constexpr long OO_XOUT  = 32772;
constexpr long OO_VFEAT = 32772L + 16777216L;

__device__ inline u16 to_bf16(float f) {
  union { float f; unsigned u; } x; x.f = f;
  unsigned r = x.u + 0x7fffu + ((x.u >> 16) & 1u);
  return (u16)(r >> 16);
}
__device__ inline u16x8 pack8(float4 a, float4 b) {
  u16x8 r;
  r[0]=to_bf16(a.x); r[1]=to_bf16(a.y); r[2]=to_bf16(a.z); r[3]=to_bf16(a.w);
  r[4]=to_bf16(b.x); r[5]=to_bf16(b.y); r[6]=to_bf16(b.z); r[7]=to_bf16(b.w);
  return r;
}

__device__ inline float bred_sum(float v, float* sm, int tid) {
  sm[tid] = v; __syncthreads();
  for (int s = 128; s > 0; s >>= 1) { if (tid < s) sm[tid] += sm[tid + s]; __syncthreads(); }
  float r = sm[0]; __syncthreads();
  return r;
}
__device__ inline float bred_max(float v, float* sm, int tid) {
  sm[tid] = v; __syncthreads();
  for (int s = 128; s > 0; s >>= 1) { if (tid < s) sm[tid] = fmaxf(sm[tid], sm[tid + s]); __syncthreads(); }
  float r = sm[0]; __syncthreads();
  return r;
}

struct GP2 {
  const void* A; const void* B; const float* bias; void* C;
  int M, N, K, lda, ldb, ldc, Hdiv;
  long sAb, sAh, sBb, sBh, sCb, sCh;
  float scale;
};

// ================= bf16 MFMA GEMM: C = epi(scale*A@B^T + bias) =================
// A: M x K row-major (bf16 if ABF else fp32); B: N x K row-major (bf16 if BBF else fp32)
// C: fp32 (ACC adds) or bf16 (CBF). Tile 128x128, BK=32, 4 waves of 4x4 16x16x32 MFMAs.
template<int EPI, bool ABF, bool BBF, bool ACC, bool CBF>
__global__ __launch_bounds__(256) void mgemm_k(GP2 p) {
  __shared__ __align__(16) u16 As[4096];
  __shared__ __align__(16) u16 Bs[4096];
  int bb = blockIdx.z / p.Hdiv, hh = blockIdx.z % p.Hdiv;
  long aoff = (long)bb * p.sAb + (long)hh * p.sAh;
  long boff = (long)bb * p.sBb + (long)hh * p.sBh;
  long coff = (long)bb * p.sCb + (long)hh * p.sCh;
  int m0 = blockIdx.x * 128, n0 = blockIdx.y * 128;
  int tid = threadIdx.x, r = tid & 127, seg = tid >> 7;
  int lane = tid & 63, wave = tid >> 6;
  int wm = (wave >> 1) * 64, wn = (wave & 1) * 64;
  int l15 = lane & 15, quad = lane >> 4;
  f32x4 acc[4][4] = {};
  for (int k0 = 0; k0 < p.K; k0 += 32) {
    bool kfull = (k0 + 32 <= p.K);
    int sidx = r * 32 + seg * 16;
    { // A stage
      int gm = m0 + r;
      if (ABF) {
        const u16* Ar = (const u16*)p.A + aoff + (long)gm * p.lda + k0 + seg * 16;
        if (kfull) {
          *(u32x4*)&As[sidx]     = *(const u32x4*)Ar;
          *(u32x4*)&As[sidx + 8] = *(const u32x4*)(Ar + 8);
        } else {
          for (int c = 0; c < 16; c++) {
            int kk = k0 + seg * 16 + c;
            As[sidx + c] = (kk < p.K) ? Ar[c] : (u16)0;
          }
        }
      } else {
        const float* Ar = (const float*)p.A + aoff + (long)gm * p.lda + k0 + seg * 16;
        if (kfull) {
          float4 f0 = ((const float4*)Ar)[0];
          float4 f1 = ((const float4*)Ar)[1];
          float4 f2 = ((const float4*)Ar)[2];
          float4 f3 = ((const float4*)Ar)[3];
          *(u16x8*)&As[sidx]     = pack8(f0, f1);
          *(u16x8*)&As[sidx + 8] = pack8(f2, f3);
        } else {
          for (int c = 0; c < 16; c++) {
            int kk = k0 + seg * 16 + c;
            As[sidx + c] = (kk < p.K) ? to_bf16(Ar[c]) : (u16)0;
          }
        }
      }
    }
    { // B stage (N x K, n-major in LDS)
      int gn = n0 + r;
      bool nv = gn < p.N;
      if (BBF) {
        const u16* Br = (const u16*)p.B + boff + (long)gn * p.ldb + k0 + seg * 16;
        if (nv && kfull) {
          *(u32x4*)&Bs[sidx]     = *(const u32x4*)Br;
          *(u32x4*)&Bs[sidx + 8] = *(const u32x4*)(Br + 8);
        } else {
          for (int c = 0; c < 16; c++) {
            int kk = k0 + seg * 16 + c;
            Bs[sidx + c] = (nv && kk < p.K) ? Br[c] : (u16)0;
          }
        }
      } else {
        const float* Br = (const float*)p.B + boff + (long)gn * p.ldb + k0 + seg * 16;
        if (nv && kfull) {
          float4 f0 = ((const float4*)Br)[0];
          float4 f1 = ((const float4*)Br)[1];
          float4 f2 = ((const float4*)Br)[2];
          float4 f3 = ((const float4*)Br)[3];
          *(u16x8*)&Bs[sidx]     = pack8(f0, f1);
          *(u16x8*)&Bs[sidx + 8] = pack8(f2, f3);
        } else {
          for (int c = 0; c < 16; c++) {
            int kk = k0 + seg * 16 + c;
            Bs[sidx + c] = (nv && kk < p.K) ? to_bf16(Br[c]) : (u16)0;
          }
        }
      }
    }
    __syncthreads();
    s8v af[4], bfr[4];
#pragma unroll
    for (int i = 0; i < 4; i++) af[i]  = *(const s8v*)&As[(wm + i * 16 + l15) * 32 + quad * 8];
#pragma unroll
    for (int j = 0; j < 4; j++) bfr[j] = *(const s8v*)&Bs[(wn + j * 16 + l15) * 32 + quad * 8];
#pragma unroll
    for (int i = 0; i < 4; i++)
#pragma unroll
      for (int j = 0; j < 4; j++)
        acc[i][j] = __builtin_amdgcn_mfma_f32_16x16x32_bf16(af[i], bfr[j], acc[i][j], 0, 0, 0);
    __syncthreads();
  }
  // epilogue: C/D layout col=lane&15, row=quad*4+reg
#pragma unroll
  for (int j = 0; j < 4; j++) {
    int col = n0 + wn + j * 16 + l15;
    if (col >= p.N) continue;
    float bv = p.bias ? p.bias[col] : 0.f;
#pragma unroll
    for (int i = 0; i < 4; i++) {
#pragma unroll
      for (int rr = 0; rr < 4; rr++) {
        int row = m0 + wm + i * 16 + quad * 4 + rr;
        float v = acc[i][j][rr] * p.scale + bv;
        if (EPI == 1) v = 0.5f * v * (1.f + erff(v * 0.70710678118654752f));
        if (EPI == 2) v = 1.f / (1.f + expf(-v));
        long ci = coff + (long)row * p.ldc + col;
        if (CBF) ((u16*)p.C)[ci] = to_bf16(v);
        else {
          float* Cp = (float*)p.C;
          if (ACC) v += Cp[ci];
          Cp[ci] = v;
        }
      }
    }
  }
}

// ================= conv1d k=3 pad=1, implicit im2col MFMA, K=(kpos,i)=3072 =========
__global__ __launch_bounds__(256) void convm_k(const float* __restrict__ x,
    const u16* __restrict__ wT, const float* __restrict__ bias, float* __restrict__ out) {
  __shared__ __align__(16) u16 As[4096];
  __shared__ __align__(16) u16 Bs[4096];
  int m0 = blockIdx.x * 128, n0 = blockIdx.y * 128;
  int b = m0 >> 8, tb = m0 & 255;
  int tid = threadIdx.x, r = tid & 127, seg = tid >> 7;
  int lane = tid & 63, wave = tid >> 6;
  int wm = (wave >> 1) * 64, wn = (wave & 1) * 64;
  int l15 = lane & 15, quad = lane >> 4;
  f32x4 acc[4][4] = {};
  for (int k0 = 0; k0 < 3072; k0 += 32) {
    int kp = k0 >> 10, i0 = (k0 & 1023) + seg * 16;
    int sidx = r * 32 + seg * 16;
    int t2 = tb + r + kp - 1;
    if (t2 >= 0 && t2 < 256) {
      const float4* src = (const float4*)(x + ((long)(b * 256 + t2)) * 1024 + i0);
      float4 f0 = src[0], f1 = src[1], f2 = src[2], f3 = src[3];
      *(u16x8*)&As[sidx]     = pack8(f0, f1);
      *(u16x8*)&As[sidx + 8] = pack8(f2, f3);
    } else {
      u16x8 z = {0, 0, 0, 0, 0, 0, 0, 0};
      *(u16x8*)&As[sidx] = z;
      *(u16x8*)&As[sidx + 8] = z;
    }
    const u16* Br = wT + (long)(n0 + r) * 3072 + k0 + seg * 16;
    *(u32x4*)&Bs[sidx]     = *(const u32x4*)Br;
    *(u32x4*)&Bs[sidx + 8] = *(const u32x4*)(Br + 8);
    __syncthreads();
    s8v af[4], bfr[4];
#pragma unroll
    for (int i = 0; i < 4; i++) af[i]  = *(const s8v*)&As[(wm + i * 16 + l15) * 32 + quad * 8];
#pragma unroll
    for (int j = 0; j < 4; j++) bfr[j] = *(const s8v*)&Bs[(wn + j * 16 + l15) * 32 + quad * 8];
#pragma unroll
    for (int i = 0; i < 4; i++)
#pragma unroll
      for (int j = 0; j < 4; j++)
        acc[i][j] = __builtin_amdgcn_mfma_f32_16x16x32_bf16(af[i], bfr[j], acc[i][j], 0, 0, 0);
    __syncthreads();
  }
#pragma unroll
  for (int j = 0; j < 4; j++) {
    int col = n0 + wn + j * 16 + l15;
    float bv = bias[col];
#pragma unroll
    for (int i = 0; i < 4; i++)
#pragma unroll
      for (int rr = 0; rr < 4; rr++) {
        int row = m0 + wm + i * 16 + quad * 4 + rr;
        float v = acc[i][j][rr] + bv;
        out[(long)row * 512 + col] = v > 0.f ? v : 0.f;
      }
  }
}

// ================= transposes / converts =================
// fp32 RxC -> bf16 CxR (R,C multiples of 32)
__global__ __launch_bounds__(256) void wtrans_k(const float* __restrict__ src,
    u16* __restrict__ dst, int R, int C) {
  __shared__ float t[32][33];
  int c0 = blockIdx.x * 32, r0 = blockIdx.y * 32;
  int tx = threadIdx.x & 31, ty = threadIdx.x >> 5;
  for (int rr = 0; rr < 32; rr += 8)
    t[ty + rr][tx] = src[(long)(r0 + ty + rr) * C + c0 + tx];
  __syncthreads();
  for (int rr = 0; rr < 32; rr += 8)
    dst[(long)(c0 + ty + rr) * R + r0 + tx] = to_bf16(t[tx][ty + rr]);
}

// conv_w (512,1024,3) -> bf16 [512][3][1024]
__global__ __launch_bounds__(256) void convw_t(const float* __restrict__ src, u16* __restrict__ dst) {
  int id = blockIdx.x * 256 + threadIdx.x;
  if (id >= 512 * 3072) return;
  int o = id / 3072, r2 = id % 3072;
  int kp = r2 >> 10, i = r2 & 1023;
  dst[id] = to_bf16(src[(long)o * 3072 + i * 3 + kp]);
}

// mem (60,512) fp32 -> bf16 [512][64] zero-padded
__global__ __launch_bounds__(256) void memtrans_k(const float* __restrict__ src, u16* __restrict__ dst) {
  int id = blockIdx.x * 256 + threadIdx.x;
  if (id >= 512 * 64) return;
  int n = id >> 6, k = id & 63;
  dst[id] = (k < 60) ? to_bf16(src[(long)k * 512 + n]) : (u16)0;
}

// v slice of qkv bf16 -> vT bf16 [bh][128][256]
__global__ __launch_bounds__(256) void vtrans_k(const u16* __restrict__ qkv, u16* __restrict__ vt) {
  __shared__ u16 t[32][33];
  int z = blockIdx.z;
  int b = z >> 2, h2 = z & 3;
  int t0 = blockIdx.x * 32, d0 = blockIdx.y * 32;
  int tx = threadIdx.x & 31, ty = threadIdx.x >> 5;
  const u16* src = qkv + (long)b * 393216 + 1024 + h2 * 128;
  for (int rr = 0; rr < 32; rr += 8)
    t[ty + rr][tx] = src[(long)(t0 + ty + rr) * 1536 + d0 + tx];
  __syncthreads();
  u16* dst = vt + (long)z * 32768;
  for (int rr = 0; rr < 32; rr += 8)
    dst[(long)(d0 + ty + rr) * 256 + t0 + tx] = t[tx][ty + rr];
}

// fp32 -> bf16 elementwise
__global__ __launch_bounds__(256) void cvt_k(const float* __restrict__ src, u16* __restrict__ dst, long n) {
  long i = (long)blockIdx.x * 256 + threadIdx.x;
  if (i < n) dst[i] = to_bf16(src[i]);
}

// ================= layernorm: fp32 in -> bf16 out =================
__global__ __launch_bounds__(256) void ln_k(const float* __restrict__ in,
    const float* __restrict__ g, const float* __restrict__ b, u16* __restrict__ out) {
  long row = blockIdx.x;
  const float* r = in + row * 512;
  int tid = threadIdx.x;
  __shared__ float sm[256];
  float x0 = r[tid], x1 = r[tid + 256];
  float mean = bred_sum(x0 + x1, sm, tid) * (1.f / 512.f);
  float d0 = x0 - mean, d1 = x1 - mean;
  float var = bred_sum(d0 * d0 + d1 * d1, sm, tid) * (1.f / 512.f);
  float inv = rsqrtf(var + 1e-5f);
  out[row * 512 + tid]       = to_bf16(d0 * inv * g[tid] + b[tid]);
  out[row * 512 + tid + 256] = to_bf16(d1 * inv * g[tid + 256] + b[tid + 256]);
}

__global__ __launch_bounds__(256) void softmax_k(float* __restrict__ s) {
  long row = blockIdx.x;
  float* r = s + row * 256;
  int tid = threadIdx.x;
  __shared__ float sm[256];
  float v = r[tid];
  float mx = bred_max(v, sm, tid);
  float e = expf(v - mx);
  float sum = bred_sum(e, sm, tid);
  r[tid] = e / sum;
}

__global__ __launch_bounds__(256) void top4_k(const float* __restrict__ att, float* __restrict__ out) {
  int i = blockIdx.x * 256 + threadIdx.x;
  if (i >= HBT) return;
  const float* a = att + (long)i * 60;
  float t0 = -1e30f, t1 = -1e30f, t2 = -1e30f, t3 = -1e30f;
  for (int k = 0; k < 60; k++) {
    float v = a[k];
    if (v > t0)      { t3 = t2; t2 = t1; t1 = t0; t0 = v; }
    else if (v > t1) { t3 = t2; t2 = t1; t1 = v; }
    else if (v > t2) { t3 = t2; t2 = v; }
    else if (v > t3) { t3 = v; }
  }
  out[i] = (t0 + t1 + t2 + t3) * 0.25f;
}

__global__ void topk17_k(const float* __restrict__ tatt, int* __restrict__ idx) {
  int b = threadIdx.x;
  if (b >= 32) return;
  const float* r = tatt + (long)b * 256;
  unsigned long long used[4] = {0, 0, 0, 0};
  for (int s = 0; s < 17; s++) {
    float best = -1e30f; int bi = 0;
    for (int t = 0; t < 256; t++) {
      if ((used[t >> 6] >> (t & 63)) & 1ull) continue;
      float v = r[t];
      if (v > best) { best = v; bi = t; }
    }
    used[bi >> 6] |= 1ull << (bi & 63);
    idx[b * 17 + s] = bi;
  }
}

__global__ __launch_bounds__(256) void gmean_k(const float* __restrict__ feats,
    const int* __restrict__ idx, float* __restrict__ out) {
  int b = blockIdx.x, tid = threadIdx.x;
  float s0 = 0.f, s1 = 0.f;
  for (int j = 0; j < 17; j++) {
    int t = idx[b * 17 + j];
    const float* r = feats + ((long)b * 256 + t) * 512;
    s0 += r[tid]; s1 += r[tid + 256];
  }
  out[(long)b * 512 + tid]       = s0 * (1.f / 17.f);
  out[(long)b * 512 + tid + 256] = s1 * (1.f / 17.f);
}

__global__ __launch_bounds__(256) void vae_k(const float* __restrict__ mu,
    const float* __restrict__ var, const float* __restrict__ eps,
    float* __restrict__ nnew, float* __restrict__ accum) {
  long i = (long)blockIdx.x * 256 + threadIdx.x;
  float m = mu[i], v = var[i], ev = expf(v);
  nnew[i] = m + eps[i] * sqrtf(ev);
  float kle = 1.f + v - m * m - ev;
  __shared__ float sm[256];
  float s = bred_sum(kle, sm, threadIdx.x);
  if (threadIdx.x == 0) atomicAdd(accum + 0, s);
}

__global__ __launch_bounds__(256) void tripcos_k(const float* __restrict__ anc,
    const float* __restrict__ pos, const float* __restrict__ neg, float* __restrict__ accum) {
  int b = blockIdx.x, tid = threadIdx.x;
  const float *a = anc + (long)b * 512, *p = pos + (long)b * 512, *n = neg + (long)b * 512;
  float a0 = a[tid], a1 = a[tid + 256], p0 = p[tid], p1 = p[tid + 256], n0 = n[tid], n1 = n[tid + 256];
  __shared__ float sm[256];
  float sa  = bred_sum(a0 * a0 + a1 * a1, sm, tid);
  float sp  = bred_sum(p0 * p0 + p1 * p1, sm, tid);
  float sn  = bred_sum(n0 * n0 + n1 * n1, sm, tid);
  float dot = bred_sum(a0 * n0 + a1 * n1, sm, tid);
  float na = sqrtf(sa), np_ = sqrtf(sp), nn = sqrtf(sn);
  float ina = 1.f / na, inp = 1.f / np_, inn = 1.f / nn;
  float d0 = a0 * ina - p0 * inp + 1e-6f, d1 = a1 * ina - p1 * inp + 1e-6f;
  float e0 = a0 * ina - n0 * inn + 1e-6f, e1 = a1 * ina - n1 * inn + 1e-6f;
  float dp2 = bred_sum(d0 * d0 + d1 * d1, sm, tid);
  float dn2 = bred_sum(e0 * e0 + e1 * e1, sm, tid);
  if (tid == 0) {
    float dp = sqrtf(dp2), dn = sqrtf(dn2);
    float t = dp - dn + 1.f;
    atomicAdd(accum + 1, t > 0.f ? t : 0.f);
    float c = 1.f - dot / (fmaxf(na, 1e-6f) * fmaxf(nn, 1e-6f));
    atomicAdd(accum + 2, c);
  }
}

__global__ __launch_bounds__(256) void dist_k(const float* __restrict__ anew,
    const float* __restrict__ nneg, float* __restrict__ accum) {
  int b = blockIdx.x, tid = threadIdx.x;
  const float *a = anew + (long)b * 512, *n = nneg + (long)b * 512;
  float a0 = a[tid], a1 = a[tid + 256], n0 = n[tid], n1 = n[tid + 256];
  __shared__ float sm[256];
  float sa = bred_sum(a0 * a0 + a1 * a1, sm, tid);
  float sn = bred_sum(n0 * n0 + n1 * n1, sm, tid);
  if (tid == 0) {
    float v = 100.f - sqrtf(sn) + sqrtf(sa);
    atomicAdd(accum + 3, v > 0.f ? v : 0.f);
  }
}

__global__ __launch_bounds__(256) void xout_k(const float* __restrict__ emb,
    const float* __restrict__ nnew, const float* __restrict__ anm,
    const float* __restrict__ anew, const float* __restrict__ nam,
    float* __restrict__ xout) {
  long i = (long)blockIdx.x * 256 + threadIdx.x;
  long row = i >> 9;
  int d = (int)(i & 511);
  long o = row * 1024 + d;
  xout[o] = emb[i];
  float v;
  if (i < HHf) v = nnew[i] + anm[i];
  else         v = anew[i - HHf] + nam[i - HHf];
  xout[o + 512] = v;
}

__global__ __launch_bounds__(256) void vfeat_k(const float* __restrict__ emb, float* __restrict__ vf) {
  __shared__ float tile[32][33];
  int b = blockIdx.z;
  int t0 = blockIdx.x * 32, d0 = blockIdx.y * 32;
  int tx = threadIdx.x & 31, ty = threadIdx.x >> 5;
  for (int r = 0; r < 32; r += 8)
    tile[ty + r][tx] = emb[((long)b * 256 + t0 + ty + r) * 512 + d0 + tx];
  __syncthreads();
  for (int r = 0; r < 32; r += 8)
    vf[((long)b * 512 + d0 + ty + r) * 256 + t0 + tx] = tile[tx][ty + r];
}

__global__ void init_k(float* accum) {
  accum[0] = 0.f; accum[1] = 0.f; accum[2] = 0.f; accum[3] = 0.f;
}

__global__ void fin_k(const float* __restrict__ accum, float* __restrict__ out) {
  out[0] = accum[1] * (1.f / 32.f);
  out[1] = -0.5f * accum[0] * (1.f / 16384.f);
  out[2] = accum[3] * (1.f / 32.f);
  out[OO_COS] = accum[2] * (1.f / 32.f);
}

static inline GP2 mk(const void* A, const void* B, const float* bias, void* C,
                     int M, int N, int K, int lda, int ldb, int ldc,
                     float scale = 1.f, int Hdiv = 1,
                     long sAb = 0, long sAh = 0, long sBb = 0, long sBh = 0,
                     long sCb = 0, long sCh = 0) {
  GP2 p; p.A = A; p.B = B; p.bias = bias; p.C = C;
  p.M = M; p.N = N; p.K = K; p.lda = lda; p.ldb = ldb; p.ldc = ldc;
  p.Hdiv = Hdiv; p.sAb = sAb; p.sAh = sAh; p.sBb = sBb; p.sBh = sBh;
  p.sCb = sCb; p.sCh = sCh; p.scale = scale;
  return p;
}

} // namespace

extern "C" void kernel_launch(void* const* d_in, const int* in_sizes, int n_in,
                              void* d_out, int out_size, void* d_ws, size_t ws_size,
                              hipStream_t stream) {
  const float* x      = (const float*)d_in[0];
  const float* epsi   = (const float*)d_in[1];
  const float* conv_w = (const float*)d_in[2];
  const float* conv_b = (const float*)d_in[3];
  const float* ln1_g  = (const float*)d_in[4];
  const float* ln1_b  = (const float*)d_in[5];
  const float* qkv_w  = (const float*)d_in[6];
  const float* out_w  = (const float*)d_in[7];
  const float* out_b  = (const float*)d_in[8];
  const float* ln2_g  = (const float*)d_in[9];
  const float* ln2_b  = (const float*)d_in[10];
  const float* ff1_w  = (const float*)d_in[11];
  const float* ff1_b  = (const float*)d_in[12];
  const float* ff2_w  = (const float*)d_in[13];
  const float* ff2_b  = (const float*)d_in[14];
  const float* a_mem  = (const float*)d_in[15];
  const float* n_mem  = (const float*)d_in[16];
  const float* mu_w   = (const float*)d_in[17];
  const float* mu_b   = (const float*)d_in[18];
  const float* var_w  = (const float*)d_in[19];
  const float* var_b  = (const float*)d_in[20];
  float* out = (float*)d_out;
  float* ws  = (float*)d_ws;

  const float ATTSCALE = 0.08838834764831845f;
  const float SIGSCALE = 0.04419417382415922f;

  float* h   = ws + F_H;
  u16* lnb   = (u16*)(ws + F_LNB);
  u16* qkvb  = (u16*)(ws + F_QKV);
  u16* vtb   = (u16*)(ws + F_VT);
  float* scf = ws + F_SC;
  u16* wqkvT = (u16*)(ws + W_QKV);
  u16* woutT = (u16*)(ws + W_OUT);
  u16* wff1T = (u16*)(ws + W_FF1);
  u16* wff2T = (u16*)(ws + W_FF2);
  u16* wmuT  = (u16*)(ws + W_MU);
  u16* wvarT = (u16*)(ws + W_VAR);
  u16* wconvT= (u16*)(ws + W_CONV);
  u16* amtT  = (u16*)(ws + W_AMT);
  u16* nmtT  = (u16*)(ws + W_NMT);

  // ---- weight transposes (fp32 KxN -> bf16 NxK) ----
  wtrans_k<<<dim3(48, 16), 256, 0, stream>>>(qkv_w,          wqkvT,          512, 1536);
  wtrans_k<<<dim3(48, 16), 256, 0, stream>>>(qkv_w + 786432, wqkvT + 786432, 512, 1536);
  wtrans_k<<<dim3(16, 16), 256, 0, stream>>>(out_w,          woutT,          512, 512);
  wtrans_k<<<dim3(16, 16), 256, 0, stream>>>(out_w + 262144, woutT + 262144, 512, 512);
  wtrans_k<<<dim3(16, 16), 256, 0, stream>>>(ff1_w,          wff1T,          512, 512);
  wtrans_k<<<dim3(16, 16), 256, 0, stream>>>(ff1_w + 262144, wff1T + 262144, 512, 512);
  wtrans_k<<<dim3(16, 16), 256, 0, stream>>>(ff2_w,          wff2T,          512, 512);
  wtrans_k<<<dim3(16, 16), 256, 0, stream>>>(ff2_w + 262144, wff2T + 262144, 512, 512);
  wtrans_k<<<dim3(16, 16), 256, 0, stream>>>(mu_w,           wmuT,           512, 512);
  wtrans_k<<<dim3(16, 16), 256, 0, stream>>>(var_w,          wvarT,          512, 512);
  convw_t<<<6144, 256, 0, stream>>>(conv_w, wconvT);
  memtrans_k<<<128, 256, 0, stream>>>(a_mem, amtT);
  memtrans_k<<<128, 256, 0, stream>>>(n_mem, nmtT);

  // ---- conv + relu -> h (fp32) ----
  convm_k<<<dim3(128, 4), 256, 0, stream>>>(x, wconvT, conv_b, h);

  // ---- transformer ----
  for (int i = 0; i < 2; i++) {
    ln_k<<<16384, 256, 0, stream>>>(h, ln1_g + i * 512, ln1_b + i * 512, lnb);
    { // qkv: (16384x512) x (1536x512)^T -> bf16
      GP2 p = mk(lnb, wqkvT + (long)i * 786432, nullptr, qkvb, 16384, 1536, 512, 512, 512, 1536);
      mgemm_k<0, true, true, false, true><<<dim3(128, 12, 1), 256, 0, stream>>>(p);
    }
    vtrans_k<<<dim3(8, 4, 256), 256, 0, stream>>>(qkvb, vtb);
    { // scores = q @ k^T * scale, per (b,h)
      GP2 p = mk(qkvb, qkvb + 512, nullptr, scf, 256, 256, 128, 1536, 1536, 256,
                 ATTSCALE, 4, 393216, 128, 393216, 128, 262144, 65536);
      mgemm_k<0, true, true, false, false><<<dim3(2, 2, 256), 256, 0, stream>>>(p);
    }
    softmax_k<<<65536, 256, 0, stream>>>(scf);
    { // o = att @ v  (B = vT bf16), write bf16 into lnb region
      GP2 p = mk(scf, vtb, nullptr, lnb, 256, 128, 256, 256, 256, 512,
                 1.f, 4, 262144, 65536, 131072, 32768, 131072, 128);
      mgemm_k<0, false, true, false, true><<<dim3(2, 1, 256), 256, 0, stream>>>(p);
    }
    { // out-proj + residual into h
      GP2 p = mk(lnb, woutT + (long)i * 262144, out_b + i * 512, h, 16384, 512, 512, 512, 512, 512);
      mgemm_k<0, true, true, true, false><<<dim3(128, 4, 1), 256, 0, stream>>>(p);
    }
    ln_k<<<16384, 256, 0, stream>>>(h, ln2_g + i * 512, ln2_b + i * 512, lnb);
    { // ff1 + gelu -> bf16 (qkvb region)
      GP2 p = mk(lnb, wff1T + (long)i * 262144, ff1_b + i * 512, qkvb, 16384, 512, 512, 512, 512, 512);
      mgemm_k<1, true, true, false, true><<<dim3(128, 4, 1), 256, 0, stream>>>(p);
    }
    { // ff2 + residual into h
      GP2 p = mk(qkvb, wff2T + (long)i * 262144, ff2_b + i * 512, h, 16384, 512, 512, 512, 512, 512);
      mgemm_k<0, true, true, true, false><<<dim3(128, 4, 1), 256, 0, stream>>>(p);
    }
  }

  // ---- memory phase ----
  u16* hb = lnb;
  cvt_k<<<32768, 256, 0, stream>>>(h, hb, 8388608);
  const float* Nx = h;
  const float* Ax = h + HHf;
  const u16* Nxb = hb;
  const u16* Axb = hb + HHf;
  float* attA  = ws + F_ATT;
  float* attNA = ws + F_ATT + 491520;
  float* attAN = ws + F_ATT + 983040;
  float* attN  = ws + F_ATT + 1474560;

  { // sigmoid attentions: A bf16, B = mem fp32 (N=60)
    GP2 p = mk(Axb, a_mem, nullptr, attA, HBT, 60, 512, 512, 512, 60, SIGSCALE);
    mgemm_k<2, true, false, false, false><<<dim3(64, 1, 1), 256, 0, stream>>>(p);
    p = mk(Axb, n_mem, nullptr, attNA, HBT, 60, 512, 512, 512, 60, SIGSCALE);
    mgemm_k<2, true, false, false, false><<<dim3(64, 1, 1), 256, 0, stream>>>(p);
    p = mk(Nxb, a_mem, nullptr, attAN, HBT, 60, 512, 512, 512, 60, SIGSCALE);
    mgemm_k<2, true, false, false, false><<<dim3(64, 1, 1), 256, 0, stream>>>(p);
    p = mk(Nxb, n_mem, nullptr, attN, HBT, 60, 512, 512, 512, 60, SIGSCALE);
    mgemm_k<2, true, false, false, false><<<dim3(64, 1, 1), 256, 0, stream>>>(p);
  }

  top4_k<<<32, 256, 0, stream>>>(attA,  out + OO_AATT);
  top4_k<<<32, 256, 0, stream>>>(attN,  out + OO_NATT);
  top4_k<<<32, 256, 0, stream>>>(attAN, out + OO_ANATT);
  top4_k<<<32, 256, 0, stream>>>(attNA, out + OO_NAATT);

  // augs = att @ mem -> bf16 (A fp32 lda=60, B = memT bf16 [512][64])
  u16* augb = (u16*)(ws + F_AUG);
  u16* augA  = augb;                 // A_aug
  u16* augN  = augb + HHf;           // N_aug
  u16* augAN = augb + 2 * HHf;       // A_Naug
  u16* augNA = augb + 3 * HHf;       // N_Aaug
  {
    GP2 p = mk(attA, amtT, nullptr, augA, HBT, 512, 60, 60, 64, 512);
    mgemm_k<0, false, true, false, true><<<dim3(64, 4, 1), 256, 0, stream>>>(p);
    p = mk(attN, nmtT, nullptr, augN, HBT, 512, 60, 60, 64, 512);
    mgemm_k<0, false, true, false, true><<<dim3(64, 4, 1), 256, 0, stream>>>(p);
    p = mk(attAN, amtT, nullptr, augAN, HBT, 512, 60, 60, 64, 512);
    mgemm_k<0, false, true, false, true><<<dim3(64, 4, 1), 256, 0, stream>>>(p);
    p = mk(attNA, nmtT, nullptr, augNA, HBT, 512, 60, 60, 64, 512);
    mgemm_k<0, false, true, false, true><<<dim3(64, 4, 1), 256, 0, stream>>>(p);
  }

  float* accum = ws + O_ACC;
  int* idxA = (int*)(ws + O_IDX);
  int* idxN = idxA + 544;
  int* idxP = idxN + 544;
  init_k<<<1, 1, 0, stream>>>(accum);

  topk17_k<<<1, 32, 0, stream>>>(out + OO_AATT,  idxA);
  topk17_k<<<1, 32, 0, stream>>>(out + OO_NATT,  idxN);
  topk17_k<<<1, 32, 0, stream>>>(out + OO_ANATT, idxP);

  gmean_k<<<32, 256, 0, stream>>>(Ax, idxA, ws + O_NEG);
  gmean_k<<<32, 256, 0, stream>>>(Nx, idxN, ws + O_ANC);
  gmean_k<<<32, 256, 0, stream>>>(Ax, idxP, ws + O_POS);
  tripcos_k<<<32, 256, 0, stream>>>(ws + O_ANC, ws + O_POS, ws + O_NEG, accum);

  // mu/var projections of N_aug; VAE
  {
    GP2 p = mk(augN, wmuT, mu_b, ws + F_MU, HBT, 512, 512, 512, 512, 512);
    mgemm_k<0, true, true, false, false><<<dim3(64, 4, 1), 256, 0, stream>>>(p);
    p = mk(augN, wvarT, var_b, ws + F_VAR, HBT, 512, 512, 512, 512, 512);
    mgemm_k<0, true, true, false, false><<<dim3(64, 4, 1), 256, 0, stream>>>(p);
  }
  vae_k<<<16384, 256, 0, stream>>>(ws + F_MU, ws + F_VAR, epsi, ws + F_NNEW, accum);

  // A_aug_new -> F_MU, A_Naug_m -> F_VAR, N_Aaug_m -> F_NAM
  {
    GP2 p = mk(augA, wmuT, mu_b, ws + F_MU, HBT, 512, 512, 512, 512, 512);
    mgemm_k<0, true, true, false, false><<<dim3(64, 4, 1), 256, 0, stream>>>(p);
    p = mk(augAN, wmuT, mu_b, ws + F_VAR, HBT, 512, 512, 512, 512, 512);
    mgemm_k<0, true, true, false, false><<<dim3(64, 4, 1), 256, 0, stream>>>(p);
    p = mk(augNA, wmuT, mu_b, ws + F_NAM, HBT, 512, 512, 512, 512, 512);
    mgemm_k<0, true, true, false, false><<<dim3(64, 4, 1), 256, 0, stream>>>(p);
  }

  gmean_k<<<32, 256, 0, stream>>>(ws + F_NNEW, idxN, ws + O_ANEW);
  gmean_k<<<32, 256, 0, stream>>>(ws + F_MU,   idxA, ws + O_NNEG);
  dist_k<<<32, 256, 0, stream>>>(ws + O_ANEW, ws + O_NNEG, accum);

  xout_k<<<32768, 256, 0, stream>>>(h, ws + F_NNEW, ws + F_VAR, ws + F_MU, ws + F_NAM,
                                    out + OO_XOUT);
  vfeat_k<<<dim3(8, 16, 64), 256, 0, stream>>>(h, out + OO_VFEAT);
  fin_k<<<1, 1, 0, stream>>>(accum, out);
}

// Round 3
// 1647.067 us; speedup vs baseline: 4.6293x; 1.8762x over previous
//
#include <hip/hip_runtime.h>
#include <math.h>

namespace {

typedef unsigned short u16;
typedef __attribute__((ext_vector_type(8))) short s8v;
typedef __attribute__((ext_vector_type(8))) unsigned short u16x8;
typedef __attribute__((ext_vector_type(4))) float f32x4;
typedef __attribute__((ext_vector_type(4))) unsigned int u32x4;

constexpr int HBT = 8192;            // 32*256
constexpr long HHf = 4194304;        // 8192*512

// ---- workspace offsets (float units) ----
constexpr long F_H    = 0;           // h / x_emb fp32 (8388608)
constexpr long F_LNB  = 8388608;     // ln / o / hbf bf16 (8388608 u16 = 4194304 fl)
constexpr long F_QKV  = 12582912;    // qkv bf16 (25165824 u16 = 12582912 fl); ff1 out reuses
constexpr long F_VT   = 25165824;    // v^T bf16
constexpr long F_SC   = 29360128;    // scores fp32 (16777216)
// phase M (QKV/VT/SC regions dead):
constexpr long F_ATT  = 12582912;    // 4 x 491520 fp32
constexpr long F_AUG  = 14548992;    // 4 x 4194304 u16 = 8388608 fl
constexpr long F_MU   = 22937600;    // fp32 4194304
constexpr long F_VAR  = 27131904;
constexpr long F_NNEW = 31326208;
constexpr long F_NAM  = 35520512;
// transposed weights (bf16), live whole launch:
constexpr long W_QKV  = 46137344;    // 2 x 786432 u16
constexpr long W_OUT  = 46923776;    // 2 x 262144 u16
constexpr long W_FF1  = 47185920;
constexpr long W_FF2  = 47448064;
constexpr long W_MU   = 47710208;    // 262144 u16
constexpr long W_VAR  = 47841280;
constexpr long W_CONV = 47972352;    // 1572864 u16
constexpr long W_AMT  = 48758784;    // 32768 u16 (512x64 padded)
constexpr long W_NMT  = 48775168;
constexpr long O_ANC  = 48791552;
constexpr long O_POS  = O_ANC + 16384;
constexpr long O_NEG  = O_POS + 16384;
constexpr long O_ANEW = O_NEG + 16384;
constexpr long O_NNEG = O_ANEW + 16384;
constexpr long O_IDX  = O_NNEG + 16384;   // 3*544 ints
constexpr long O_ACC  = O_IDX + 1632;     // 4 floats

// ---- output offsets ----
constexpr long OO_AATT  = 3;
constexpr long OO_NATT  = 3 + 8192;
constexpr long OO_ANATT = 3 + 16384;
constexpr long OO_NAATT = 3 + 24576;
constexpr long OO_COS   = 32771;
constexpr long OO_XOUT  = 32772;
constexpr long OO_VFEAT = 32772L + 16777216L;

__device__ inline u16 to_bf16(float f) {
  union { float f; unsigned u; } x; x.f = f;
  unsigned r = x.u + 0x7fffu + ((x.u >> 16) & 1u);
  return (u16)(r >> 16);
}
__device__ inline u16x8 pack8(float4 a, float4 b) {
  u16x8 r;
  r[0]=to_bf16(a.x); r[1]=to_bf16(a.y); r[2]=to_bf16(a.z); r[3]=to_bf16(a.w);
  r[4]=to_bf16(b.x); r[5]=to_bf16(b.y); r[6]=to_bf16(b.z); r[7]=to_bf16(b.w);
  return r;
}

__device__ inline float bred_sum(float v, float* sm, int tid) {
  sm[tid] = v; __syncthreads();
  for (int s = 128; s > 0; s >>= 1) { if (tid < s) sm[tid] += sm[tid + s]; __syncthreads(); }
  float r = sm[0]; __syncthreads();
  return r;
}

struct GP2 {
  const void* A; const void* B; const float* bias; void* C;
  int M, N, K, lda, ldb, ldc, Hdiv;
  long sAb, sAh, sBb, sBh, sCb, sCh;
  float scale;
};

// ================= bf16 MFMA GEMM: C = epi(scale*A@B^T + bias) =================
template<int EPI, bool ABF, bool BBF, bool ACC, bool CBF>
__global__ __launch_bounds__(256) void mgemm_k(GP2 p) {
  __shared__ __align__(16) u16 As[4096];
  __shared__ __align__(16) u16 Bs[4096];
  int bb = blockIdx.z / p.Hdiv, hh = blockIdx.z % p.Hdiv;
  long aoff = (long)bb * p.sAb + (long)hh * p.sAh;
  long boff = (long)bb * p.sBb + (long)hh * p.sBh;
  long coff = (long)bb * p.sCb + (long)hh * p.sCh;
  int m0 = blockIdx.x * 128, n0 = blockIdx.y * 128;
  int tid = threadIdx.x, r = tid & 127, seg = tid >> 7;
  int lane = tid & 63, wave = tid >> 6;
  int wm = (wave >> 1) * 64, wn = (wave & 1) * 64;
  int l15 = lane & 15, quad = lane >> 4;
  f32x4 acc[4][4] = {};
  for (int k0 = 0; k0 < p.K; k0 += 32) {
    bool kfull = (k0 + 32 <= p.K);
    int sidx = r * 32 + seg * 16;
    { // A stage
      int gm = m0 + r;
      if (ABF) {
        const u16* Ar = (const u16*)p.A + aoff + (long)gm * p.lda + k0 + seg * 16;
        if (kfull) {
          *(u32x4*)&As[sidx]     = *(const u32x4*)Ar;
          *(u32x4*)&As[sidx + 8] = *(const u32x4*)(Ar + 8);
        } else {
          for (int c = 0; c < 16; c++) {
            int kk = k0 + seg * 16 + c;
            As[sidx + c] = (kk < p.K) ? Ar[c] : (u16)0;
          }
        }
      } else {
        const float* Ar = (const float*)p.A + aoff + (long)gm * p.lda + k0 + seg * 16;
        if (kfull) {
          float4 f0 = ((const float4*)Ar)[0];
          float4 f1 = ((const float4*)Ar)[1];
          float4 f2 = ((const float4*)Ar)[2];
          float4 f3 = ((const float4*)Ar)[3];
          *(u16x8*)&As[sidx]     = pack8(f0, f1);
          *(u16x8*)&As[sidx + 8] = pack8(f2, f3);
        } else {
          for (int c = 0; c < 16; c++) {
            int kk = k0 + seg * 16 + c;
            As[sidx + c] = (kk < p.K) ? to_bf16(Ar[c]) : (u16)0;
          }
        }
      }
    }
    { // B stage (N x K)
      int gn = n0 + r;
      bool nv = gn < p.N;
      if (BBF) {
        const u16* Br = (const u16*)p.B + boff + (long)gn * p.ldb + k0 + seg * 16;
        if (nv && kfull) {
          *(u32x4*)&Bs[sidx]     = *(const u32x4*)Br;
          *(u32x4*)&Bs[sidx + 8] = *(const u32x4*)(Br + 8);
        } else {
          for (int c = 0; c < 16; c++) {
            int kk = k0 + seg * 16 + c;
            Bs[sidx + c] = (nv && kk < p.K) ? Br[c] : (u16)0;
          }
        }
      } else {
        const float* Br = (const float*)p.B + boff + (long)gn * p.ldb + k0 + seg * 16;
        if (nv && kfull) {
          float4 f0 = ((const float4*)Br)[0];
          float4 f1 = ((const float4*)Br)[1];
          float4 f2 = ((const float4*)Br)[2];
          float4 f3 = ((const float4*)Br)[3];
          *(u16x8*)&Bs[sidx]     = pack8(f0, f1);
          *(u16x8*)&Bs[sidx + 8] = pack8(f2, f3);
        } else {
          for (int c = 0; c < 16; c++) {
            int kk = k0 + seg * 16 + c;
            Bs[sidx + c] = (nv && kk < p.K) ? to_bf16(Br[c]) : (u16)0;
          }
        }
      }
    }
    __syncthreads();
    s8v af[4], bfr[4];
#pragma unroll
    for (int i = 0; i < 4; i++) af[i]  = *(const s8v*)&As[(wm + i * 16 + l15) * 32 + quad * 8];
#pragma unroll
    for (int j = 0; j < 4; j++) bfr[j] = *(const s8v*)&Bs[(wn + j * 16 + l15) * 32 + quad * 8];
#pragma unroll
    for (int i = 0; i < 4; i++)
#pragma unroll
      for (int j = 0; j < 4; j++)
        acc[i][j] = __builtin_amdgcn_mfma_f32_16x16x32_bf16(af[i], bfr[j], acc[i][j], 0, 0, 0);
    __syncthreads();
  }
#pragma unroll
  for (int j = 0; j < 4; j++) {
    int col = n0 + wn + j * 16 + l15;
    if (col >= p.N) continue;
    float bv = p.bias ? p.bias[col] : 0.f;
#pragma unroll
    for (int i = 0; i < 4; i++) {
#pragma unroll
      for (int rr = 0; rr < 4; rr++) {
        int row = m0 + wm + i * 16 + quad * 4 + rr;
        float v = acc[i][j][rr] * p.scale + bv;
        if (EPI == 1) v = 0.5f * v * (1.f + erff(v * 0.70710678118654752f));
        if (EPI == 2) v = 1.f / (1.f + expf(-v));
        long ci = coff + (long)row * p.ldc + col;
        if (CBF) ((u16*)p.C)[ci] = to_bf16(v);
        else {
          float* Cp = (float*)p.C;
          if (ACC) v += Cp[ci];
          Cp[ci] = v;
        }
      }
    }
  }
}

// ================= conv1d k=3 pad=1, implicit im2col MFMA =================
__global__ __launch_bounds__(256) void convm_k(const float* __restrict__ x,
    const u16* __restrict__ wT, const float* __restrict__ bias, float* __restrict__ out) {
  __shared__ __align__(16) u16 As[4096];
  __shared__ __align__(16) u16 Bs[4096];
  int m0 = blockIdx.x * 128, n0 = blockIdx.y * 128;
  int b = m0 >> 8, tb = m0 & 255;
  int tid = threadIdx.x, r = tid & 127, seg = tid >> 7;
  int lane = tid & 63, wave = tid >> 6;
  int wm = (wave >> 1) * 64, wn = (wave & 1) * 64;
  int l15 = lane & 15, quad = lane >> 4;
  f32x4 acc[4][4] = {};
  for (int k0 = 0; k0 < 3072; k0 += 32) {
    int kp = k0 >> 10, i0 = (k0 & 1023) + seg * 16;
    int sidx = r * 32 + seg * 16;
    int t2 = tb + r + kp - 1;
    if (t2 >= 0 && t2 < 256) {
      const float4* src = (const float4*)(x + ((long)(b * 256 + t2)) * 1024 + i0);
      float4 f0 = src[0], f1 = src[1], f2 = src[2], f3 = src[3];
      *(u16x8*)&As[sidx]     = pack8(f0, f1);
      *(u16x8*)&As[sidx + 8] = pack8(f2, f3);
    } else {
      u16x8 z = {0, 0, 0, 0, 0, 0, 0, 0};
      *(u16x8*)&As[sidx] = z;
      *(u16x8*)&As[sidx + 8] = z;
    }
    const u16* Br = wT + (long)(n0 + r) * 3072 + k0 + seg * 16;
    *(u32x4*)&Bs[sidx]     = *(const u32x4*)Br;
    *(u32x4*)&Bs[sidx + 8] = *(const u32x4*)(Br + 8);
    __syncthreads();
    s8v af[4], bfr[4];
#pragma unroll
    for (int i = 0; i < 4; i++) af[i]  = *(const s8v*)&As[(wm + i * 16 + l15) * 32 + quad * 8];
#pragma unroll
    for (int j = 0; j < 4; j++) bfr[j] = *(const s8v*)&Bs[(wn + j * 16 + l15) * 32 + quad * 8];
#pragma unroll
    for (int i = 0; i < 4; i++)
#pragma unroll
      for (int j = 0; j < 4; j++)
        acc[i][j] = __builtin_amdgcn_mfma_f32_16x16x32_bf16(af[i], bfr[j], acc[i][j], 0, 0, 0);
    __syncthreads();
  }
#pragma unroll
  for (int j = 0; j < 4; j++) {
    int col = n0 + wn + j * 16 + l15;
    float bv = bias[col];
#pragma unroll
    for (int i = 0; i < 4; i++)
#pragma unroll
      for (int rr = 0; rr < 4; rr++) {
        int row = m0 + wm + i * 16 + quad * 4 + rr;
        float v = acc[i][j][rr] + bv;
        out[(long)row * 512 + col] = v > 0.f ? v : 0.f;
      }
  }
}

// ================= transposes / converts =================
__global__ __launch_bounds__(256) void wtrans_k(const float* __restrict__ src,
    u16* __restrict__ dst, int R, int C) {
  __shared__ float t[32][33];
  int c0 = blockIdx.x * 32, r0 = blockIdx.y * 32;
  int tx = threadIdx.x & 31, ty = threadIdx.x >> 5;
  for (int rr = 0; rr < 32; rr += 8)
    t[ty + rr][tx] = src[(long)(r0 + ty + rr) * C + c0 + tx];
  __syncthreads();
  for (int rr = 0; rr < 32; rr += 8)
    dst[(long)(c0 + ty + rr) * R + r0 + tx] = to_bf16(t[tx][ty + rr]);
}

__global__ __launch_bounds__(256) void convw_t(const float* __restrict__ src, u16* __restrict__ dst) {
  int id = blockIdx.x * 256 + threadIdx.x;
  if (id >= 512 * 3072) return;
  int o = id / 3072, r2 = id % 3072;
  int kp = r2 >> 10, i = r2 & 1023;
  dst[id] = to_bf16(src[(long)o * 3072 + i * 3 + kp]);
}

__global__ __launch_bounds__(256) void memtrans_k(const float* __restrict__ src, u16* __restrict__ dst) {
  int id = blockIdx.x * 256 + threadIdx.x;
  if (id >= 512 * 64) return;
  int n = id >> 6, k = id & 63;
  dst[id] = (k < 60) ? to_bf16(src[(long)k * 512 + n]) : (u16)0;
}

__global__ __launch_bounds__(256) void vtrans_k(const u16* __restrict__ qkv, u16* __restrict__ vt) {
  __shared__ u16 t[32][33];
  int z = blockIdx.z;
  int b = z >> 2, h2 = z & 3;
  int t0 = blockIdx.x * 32, d0 = blockIdx.y * 32;
  int tx = threadIdx.x & 31, ty = threadIdx.x >> 5;
  const u16* src = qkv + (long)b * 393216 + 1024 + h2 * 128;
  for (int rr = 0; rr < 32; rr += 8)
    t[ty + rr][tx] = src[(long)(t0 + ty + rr) * 1536 + d0 + tx];
  __syncthreads();
  u16* dst = vt + (long)z * 32768;
  for (int rr = 0; rr < 32; rr += 8)
    dst[(long)(d0 + ty + rr) * 256 + t0 + tx] = t[tx][ty + rr];
}

__global__ __launch_bounds__(256) void cvt_k(const float* __restrict__ src, u16* __restrict__ dst, long n) {
  long i = (long)blockIdx.x * 256 + threadIdx.x;
  if (i < n) dst[i] = to_bf16(src[i]);
}

// ================= layernorm: wave-per-row, fp32 in -> bf16 out =================
__global__ __launch_bounds__(256) void ln_k(const float* __restrict__ in,
    const float* __restrict__ g, const float* __restrict__ b, u16* __restrict__ out) {
  int wave = threadIdx.x >> 6, lane = threadIdx.x & 63;
  long row = (long)blockIdx.x * 4 + wave;
  const float* r = in + row * 512 + lane * 8;
  float4 x0 = ((const float4*)r)[0];
  float4 x1 = ((const float4*)r)[1];
  float s = x0.x + x0.y + x0.z + x0.w + x1.x + x1.y + x1.z + x1.w;
  for (int off = 32; off; off >>= 1) s += __shfl_xor(s, off);
  float mean = s * (1.f / 512.f);
  float d[8] = {x0.x - mean, x0.y - mean, x0.z - mean, x0.w - mean,
                x1.x - mean, x1.y - mean, x1.z - mean, x1.w - mean};
  float q = 0.f;
#pragma unroll
  for (int i = 0; i < 8; i++) q += d[i] * d[i];
  for (int off = 32; off; off >>= 1) q += __shfl_xor(q, off);
  float inv = rsqrtf(q * (1.f / 512.f) + 1e-5f);
  const float4* gp = (const float4*)(g + lane * 8);
  const float4* bp = (const float4*)(b + lane * 8);
  float4 g0 = gp[0], g1 = gp[1], b0 = bp[0], b1 = bp[1];
  float gv[8] = {g0.x, g0.y, g0.z, g0.w, g1.x, g1.y, g1.z, g1.w};
  float bv[8] = {b0.x, b0.y, b0.z, b0.w, b1.x, b1.y, b1.z, b1.w};
  u16x8 o;
#pragma unroll
  for (int i = 0; i < 8; i++) o[i] = to_bf16(d[i] * inv * gv[i] + bv[i]);
  *(u16x8*)(out + row * 512 + lane * 8) = o;
}

// ================= softmax: wave-per-row (rows of 256) =================
__global__ __launch_bounds__(256) void softmax_k(float* __restrict__ s) {
  int wave = threadIdx.x >> 6, lane = threadIdx.x & 63;
  long row = (long)blockIdx.x * 4 + wave;
  float* r = s + row * 256 + lane * 4;
  float4 v = *(float4*)r;
  float mx = fmaxf(fmaxf(v.x, v.y), fmaxf(v.z, v.w));
  for (int off = 32; off; off >>= 1) mx = fmaxf(mx, __shfl_xor(mx, off));
  v.x = expf(v.x - mx); v.y = expf(v.y - mx); v.z = expf(v.z - mx); v.w = expf(v.w - mx);
  float sum = v.x + v.y + v.z + v.w;
  for (int off = 32; off; off >>= 1) sum += __shfl_xor(sum, off);
  float is = 1.f / sum;
  v.x *= is; v.y *= is; v.z *= is; v.w *= is;
  *(float4*)r = v;
}

__global__ __launch_bounds__(256) void top4_k(const float* __restrict__ att, float* __restrict__ out) {
  int i = blockIdx.x * 256 + threadIdx.x;
  if (i >= HBT) return;
  const float* a = att + (long)i * 60;
  float t0 = -1e30f, t1 = -1e30f, t2 = -1e30f, t3 = -1e30f;
  for (int k = 0; k < 60; k++) {
    float v = a[k];
    if (v > t0)      { t3 = t2; t2 = t1; t1 = t0; t0 = v; }
    else if (v > t1) { t3 = t2; t2 = t1; t1 = v; }
    else if (v > t2) { t3 = t2; t2 = v; }
    else if (v > t3) { t3 = v; }
  }
  out[i] = (t0 + t1 + t2 + t3) * 0.25f;
}

// ========== top-17 over 256: block-parallel iterative argmax, 1 block/row =====
__global__ __launch_bounds__(256) void topk17_k(const float* __restrict__ tatt, int* __restrict__ idx) {
  int b = blockIdx.x, tid = threadIdx.x;
  __shared__ float sv[256];
  __shared__ int si[256];
  float v = tatt[(long)b * 256 + tid];
  for (int s = 0; s < 17; s++) {
    sv[tid] = v; si[tid] = tid;
    __syncthreads();
    for (int off = 128; off > 0; off >>= 1) {
      if (tid < off) {
        float v2 = sv[tid + off]; int i2 = si[tid + off];
        if (v2 > sv[tid] || (v2 == sv[tid] && i2 < si[tid])) { sv[tid] = v2; si[tid] = i2; }
      }
      __syncthreads();
    }
    int win = si[0];
    if (tid == 0) idx[b * 17 + s] = win;
    if (tid == win) v = -1e30f;
    __syncthreads();
  }
}

__global__ __launch_bounds__(256) void gmean_k(const float* __restrict__ feats,
    const int* __restrict__ idx, float* __restrict__ out) {
  int b = blockIdx.x, tid = threadIdx.x;
  float s0 = 0.f, s1 = 0.f;
  for (int j = 0; j < 17; j++) {
    int t = idx[b * 17 + j];
    const float* r = feats + ((long)b * 256 + t) * 512;
    s0 += r[tid]; s1 += r[tid + 256];
  }
  out[(long)b * 512 + tid]       = s0 * (1.f / 17.f);
  out[(long)b * 512 + tid + 256] = s1 * (1.f / 17.f);
}

__global__ __launch_bounds__(256) void vae_k(const float* __restrict__ mu,
    const float* __restrict__ var, const float* __restrict__ eps,
    float* __restrict__ nnew, float* __restrict__ accum) {
  long i = (long)blockIdx.x * 256 + threadIdx.x;
  float m = mu[i], v = var[i], ev = expf(v);
  nnew[i] = m + eps[i] * sqrtf(ev);
  float kle = 1.f + v - m * m - ev;
  __shared__ float sm[256];
  float s = bred_sum(kle, sm, threadIdx.x);
  if (threadIdx.x == 0) atomicAdd(accum + 0, s);
}

__global__ __launch_bounds__(256) void tripcos_k(const float* __restrict__ anc,
    const float* __restrict__ pos, const float* __restrict__ neg, float* __restrict__ accum) {
  int b = blockIdx.x, tid = threadIdx.x;
  const float *a = anc + (long)b * 512, *p = pos + (long)b * 512, *n = neg + (long)b * 512;
  float a0 = a[tid], a1 = a[tid + 256], p0 = p[tid], p1 = p[tid + 256], n0 = n[tid], n1 = n[tid + 256];
  __shared__ float sm[256];
  float sa  = bred_sum(a0 * a0 + a1 * a1, sm, tid);
  float sp  = bred_sum(p0 * p0 + p1 * p1, sm, tid);
  float sn  = bred_sum(n0 * n0 + n1 * n1, sm, tid);
  float dot = bred_sum(a0 * n0 + a1 * n1, sm, tid);
  float na = sqrtf(sa), np_ = sqrtf(sp), nn = sqrtf(sn);
  float ina = 1.f / na, inp = 1.f / np_, inn = 1.f / nn;
  float d0 = a0 * ina - p0 * inp + 1e-6f, d1 = a1 * ina - p1 * inp + 1e-6f;
  float e0 = a0 * ina - n0 * inn + 1e-6f, e1 = a1 * ina - n1 * inn + 1e-6f;
  float dp2 = bred_sum(d0 * d0 + d1 * d1, sm, tid);
  float dn2 = bred_sum(e0 * e0 + e1 * e1, sm, tid);
  if (tid == 0) {
    float dp = sqrtf(dp2), dn = sqrtf(dn2);
    float t = dp - dn + 1.f;
    atomicAdd(accum + 1, t > 0.f ? t : 0.f);
    float c = 1.f - dot / (fmaxf(na, 1e-6f) * fmaxf(nn, 1e-6f));
    atomicAdd(accum + 2, c);
  }
}

__global__ __launch_bounds__(256) void dist_k(const float* __restrict__ anew,
    const float* __restrict__ nneg, float* __restrict__ accum) {
  int b = blockIdx.x, tid = threadIdx.x;
  const float *a = anew + (long)b * 512, *n = nneg + (long)b * 512;
  float a0 = a[tid], a1 = a[tid + 256], n0 = n[tid], n1 = n[tid + 256];
  __shared__ float sm[256];
  float sa = bred_sum(a0 * a0 + a1 * a1, sm, tid);
  float sn = bred_sum(n0 * n0 + n1 * n1, sm, tid);
  if (tid == 0) {
    float v = 100.f - sqrtf(sn) + sqrtf(sa);
    atomicAdd(accum + 3, v > 0.f ? v : 0.f);
  }
}

__global__ __launch_bounds__(256) void xout_k(const float* __restrict__ emb,
    const float* __restrict__ nnew, const float* __restrict__ anm,
    const float* __restrict__ anew, const float* __restrict__ nam,
    float* __restrict__ xout) {
  long i = (long)blockIdx.x * 256 + threadIdx.x;
  long row = i >> 9;
  int d = (int)(i & 511);
  long o = row * 1024 + d;
  xout[o] = emb[i];
  float v;
  if (i < HHf) v = nnew[i] + anm[i];
  else         v = anew[i - HHf] + nam[i - HHf];
  xout[o + 512] = v;
}

__global__ __launch_bounds__(256) void vfeat_k(const float* __restrict__ emb, float* __restrict__ vf) {
  __shared__ float tile[32][33];
  int b = blockIdx.z;
  int t0 = blockIdx.x * 32, d0 = blockIdx.y * 32;
  int tx = threadIdx.x & 31, ty = threadIdx.x >> 5;
  for (int r = 0; r < 32; r += 8)
    tile[ty + r][tx] = emb[((long)b * 256 + t0 + ty + r) * 512 + d0 + tx];
  __syncthreads();
  for (int r = 0; r < 32; r += 8)
    vf[((long)b * 512 + d0 + ty + r) * 256 + t0 + tx] = tile[tx][ty + r];
}

__global__ void init_k(float* accum) {
  accum[0] = 0.f; accum[1] = 0.f; accum[2] = 0.f; accum[3] = 0.f;
}

__global__ void fin_k(const float* __restrict__ accum, float* __restrict__ out) {
  out[0] = accum[1] * (1.f / 32.f);
  out[1] = -0.5f * accum[0] * (1.f / 16384.f);
  out[2] = accum[3] * (1.f / 32.f);
  out[OO_COS] = accum[2] * (1.f / 32.f);
}

static inline GP2 mk(const void* A, const void* B, const float* bias, void* C,
                     int M, int N, int K, int lda, int ldb, int ldc,
                     float scale = 1.f, int Hdiv = 1,
                     long sAb = 0, long sAh = 0, long sBb = 0, long sBh = 0,
                     long sCb = 0, long sCh = 0) {
  GP2 p; p.A = A; p.B = B; p.bias = bias; p.C = C;
  p.M = M; p.N = N; p.K = K; p.lda = lda; p.ldb = ldb; p.ldc = ldc;
  p.Hdiv = Hdiv; p.sAb = sAb; p.sAh = sAh; p.sBb = sBb; p.sBh = sBh;
  p.sCb = sCb; p.sCh = sCh; p.scale = scale;
  return p;
}

} // namespace

extern "C" void kernel_launch(void* const* d_in, const int* in_sizes, int n_in,
                              void* d_out, int out_size, void* d_ws, size_t ws_size,
                              hipStream_t stream) {
  const float* x      = (const float*)d_in[0];
  const float* epsi   = (const float*)d_in[1];
  const float* conv_w = (const float*)d_in[2];
  const float* conv_b = (const float*)d_in[3];
  const float* ln1_g  = (const float*)d_in[4];
  const float* ln1_b  = (const float*)d_in[5];
  const float* qkv_w  = (const float*)d_in[6];
  const float* out_w  = (const float*)d_in[7];
  const float* out_b  = (const float*)d_in[8];
  const float* ln2_g  = (const float*)d_in[9];
  const float* ln2_b  = (const float*)d_in[10];
  const float* ff1_w  = (const float*)d_in[11];
  const float* ff1_b  = (const float*)d_in[12];
  const float* ff2_w  = (const float*)d_in[13];
  const float* ff2_b  = (const float*)d_in[14];
  const float* a_mem  = (const float*)d_in[15];
  const float* n_mem  = (const float*)d_in[16];
  const float* mu_w   = (const float*)d_in[17];
  const float* mu_b   = (const float*)d_in[18];
  const float* var_w  = (const float*)d_in[19];
  const float* var_b  = (const float*)d_in[20];
  float* out = (float*)d_out;
  float* ws  = (float*)d_ws;

  const float ATTSCALE = 0.08838834764831845f;
  const float SIGSCALE = 0.04419417382415922f;

  float* h   = ws + F_H;
  u16* lnb   = (u16*)(ws + F_LNB);
  u16* qkvb  = (u16*)(ws + F_QKV);
  u16* vtb   = (u16*)(ws + F_VT);
  float* scf = ws + F_SC;
  u16* wqkvT = (u16*)(ws + W_QKV);
  u16* woutT = (u16*)(ws + W_OUT);
  u16* wff1T = (u16*)(ws + W_FF1);
  u16* wff2T = (u16*)(ws + W_FF2);
  u16* wmuT  = (u16*)(ws + W_MU);
  u16* wvarT = (u16*)(ws + W_VAR);
  u16* wconvT= (u16*)(ws + W_CONV);
  u16* amtT  = (u16*)(ws + W_AMT);
  u16* nmtT  = (u16*)(ws + W_NMT);

  // ---- weight transposes ----
  wtrans_k<<<dim3(48, 16), 256, 0, stream>>>(qkv_w,          wqkvT,          512, 1536);
  wtrans_k<<<dim3(48, 16), 256, 0, stream>>>(qkv_w + 786432, wqkvT + 786432, 512, 1536);
  wtrans_k<<<dim3(16, 16), 256, 0, stream>>>(out_w,          woutT,          512, 512);
  wtrans_k<<<dim3(16, 16), 256, 0, stream>>>(out_w + 262144, woutT + 262144, 512, 512);
  wtrans_k<<<dim3(16, 16), 256, 0, stream>>>(ff1_w,          wff1T,          512, 512);
  wtrans_k<<<dim3(16, 16), 256, 0, stream>>>(ff1_w + 262144, wff1T + 262144, 512, 512);
  wtrans_k<<<dim3(16, 16), 256, 0, stream>>>(ff2_w,          wff2T,          512, 512);
  wtrans_k<<<dim3(16, 16), 256, 0, stream>>>(ff2_w + 262144, wff2T + 262144, 512, 512);
  wtrans_k<<<dim3(16, 16), 256, 0, stream>>>(mu_w,           wmuT,           512, 512);
  wtrans_k<<<dim3(16, 16), 256, 0, stream>>>(var_w,          wvarT,          512, 512);
  convw_t<<<6144, 256, 0, stream>>>(conv_w, wconvT);
  memtrans_k<<<128, 256, 0, stream>>>(a_mem, amtT);
  memtrans_k<<<128, 256, 0, stream>>>(n_mem, nmtT);

  // ---- conv + relu -> h ----
  convm_k<<<dim3(128, 4), 256, 0, stream>>>(x, wconvT, conv_b, h);

  // ---- transformer ----
  for (int i = 0; i < 2; i++) {
    ln_k<<<4096, 256, 0, stream>>>(h, ln1_g + i * 512, ln1_b + i * 512, lnb);
    {
      GP2 p = mk(lnb, wqkvT + (long)i * 786432, nullptr, qkvb, 16384, 1536, 512, 512, 512, 1536);
      mgemm_k<0, true, true, false, true><<<dim3(128, 12, 1), 256, 0, stream>>>(p);
    }
    vtrans_k<<<dim3(8, 4, 256), 256, 0, stream>>>(qkvb, vtb);
    {
      GP2 p = mk(qkvb, qkvb + 512, nullptr, scf, 256, 256, 128, 1536, 1536, 256,
                 ATTSCALE, 4, 393216, 128, 393216, 128, 262144, 65536);
      mgemm_k<0, true, true, false, false><<<dim3(2, 2, 256), 256, 0, stream>>>(p);
    }
    softmax_k<<<16384, 256, 0, stream>>>(scf);
    {
      GP2 p = mk(scf, vtb, nullptr, lnb, 256, 128, 256, 256, 256, 512,
                 1.f, 4, 262144, 65536, 131072, 32768, 131072, 128);
      mgemm_k<0, false, true, false, true><<<dim3(2, 1, 256), 256, 0, stream>>>(p);
    }
    {
      GP2 p = mk(lnb, woutT + (long)i * 262144, out_b + i * 512, h, 16384, 512, 512, 512, 512, 512);
      mgemm_k<0, true, true, true, false><<<dim3(128, 4, 1), 256, 0, stream>>>(p);
    }
    ln_k<<<4096, 256, 0, stream>>>(h, ln2_g + i * 512, ln2_b + i * 512, lnb);
    {
      GP2 p = mk(lnb, wff1T + (long)i * 262144, ff1_b + i * 512, qkvb, 16384, 512, 512, 512, 512, 512);
      mgemm_k<1, true, true, false, true><<<dim3(128, 4, 1), 256, 0, stream>>>(p);
    }
    {
      GP2 p = mk(qkvb, wff2T + (long)i * 262144, ff2_b + i * 512, h, 16384, 512, 512, 512, 512, 512);
      mgemm_k<0, true, true, true, false><<<dim3(128, 4, 1), 256, 0, stream>>>(p);
    }
  }

  // ---- memory phase ----
  u16* hb = lnb;
  cvt_k<<<32768, 256, 0, stream>>>(h, hb, 8388608);
  const float* Nx = h;
  const float* Ax = h + HHf;
  const u16* Nxb = hb;
  const u16* Axb = hb + HHf;
  float* attA  = ws + F_ATT;
  float* attNA = ws + F_ATT + 491520;
  float* attAN = ws + F_ATT + 983040;
  float* attN  = ws + F_ATT + 1474560;

  {
    GP2 p = mk(Axb, a_mem, nullptr, attA, HBT, 60, 512, 512, 512, 60, SIGSCALE);
    mgemm_k<2, true, false, false, false><<<dim3(64, 1, 1), 256, 0, stream>>>(p);
    p = mk(Axb, n_mem, nullptr, attNA, HBT, 60, 512, 512, 512, 60, SIGSCALE);
    mgemm_k<2, true, false, false, false><<<dim3(64, 1, 1), 256, 0, stream>>>(p);
    p = mk(Nxb, a_mem, nullptr, attAN, HBT, 60, 512, 512, 512, 60, SIGSCALE);
    mgemm_k<2, true, false, false, false><<<dim3(64, 1, 1), 256, 0, stream>>>(p);
    p = mk(Nxb, n_mem, nullptr, attN, HBT, 60, 512, 512, 512, 60, SIGSCALE);
    mgemm_k<2, true, false, false, false><<<dim3(64, 1, 1), 256, 0, stream>>>(p);
  }

  top4_k<<<32, 256, 0, stream>>>(attA,  out + OO_AATT);
  top4_k<<<32, 256, 0, stream>>>(attN,  out + OO_NATT);
  top4_k<<<32, 256, 0, stream>>>(attAN, out + OO_ANATT);
  top4_k<<<32, 256, 0, stream>>>(attNA, out + OO_NAATT);

  u16* augb = (u16*)(ws + F_AUG);
  u16* augA  = augb;
  u16* augN  = augb + HHf;
  u16* augAN = augb + 2 * HHf;
  u16* augNA = augb + 3 * HHf;
  {
    GP2 p = mk(attA, amtT, nullptr, augA, HBT, 512, 60, 60, 64, 512);
    mgemm_k<0, false, true, false, true><<<dim3(64, 4, 1), 256, 0, stream>>>(p);
    p = mk(attN, nmtT, nullptr, augN, HBT, 512, 60, 60, 64, 512);
    mgemm_k<0, false, true, false, true><<<dim3(64, 4, 1), 256, 0, stream>>>(p);
    p = mk(attAN, amtT, nullptr, augAN, HBT, 512, 60, 60, 64, 512);
    mgemm_k<0, false, true, false, true><<<dim3(64, 4, 1), 256, 0, stream>>>(p);
    p = mk(attNA, nmtT, nullptr, augNA, HBT, 512, 60, 60, 64, 512);
    mgemm_k<0, false, true, false, true><<<dim3(64, 4, 1), 256, 0, stream>>>(p);
  }

  float* accum = ws + O_ACC;
  int* idxA = (int*)(ws + O_IDX);
  int* idxN = idxA + 544;
  int* idxP = idxN + 544;
  init_k<<<1, 1, 0, stream>>>(accum);

  topk17_k<<<32, 256, 0, stream>>>(out + OO_AATT,  idxA);
  topk17_k<<<32, 256, 0, stream>>>(out + OO_NATT,  idxN);
  topk17_k<<<32, 256, 0, stream>>>(out + OO_ANATT, idxP);

  gmean_k<<<32, 256, 0, stream>>>(Ax, idxA, ws + O_NEG);
  gmean_k<<<32, 256, 0, stream>>>(Nx, idxN, ws + O_ANC);
  gmean_k<<<32, 256, 0, stream>>>(Ax, idxP, ws + O_POS);
  tripcos_k<<<32, 256, 0, stream>>>(ws + O_ANC, ws + O_POS, ws + O_NEG, accum);

  {
    GP2 p = mk(augN, wmuT, mu_b, ws + F_MU, HBT, 512, 512, 512, 512, 512);
    mgemm_k<0, true, true, false, false><<<dim3(64, 4, 1), 256, 0, stream>>>(p);
    p = mk(augN, wvarT, var_b, ws + F_VAR, HBT, 512, 512, 512, 512, 512);
    mgemm_k<0, true, true, false, false><<<dim3(64, 4, 1), 256, 0, stream>>>(p);
  }
  vae_k<<<16384, 256, 0, stream>>>(ws + F_MU, ws + F_VAR, epsi, ws + F_NNEW, accum);

  {
    GP2 p = mk(augA, wmuT, mu_b, ws + F_MU, HBT, 512, 512, 512, 512, 512);
    mgemm_k<0, true, true, false, false><<<dim3(64, 4, 1), 256, 0, stream>>>(p);
    p = mk(augAN, wmuT, mu_b, ws + F_VAR, HBT, 512, 512, 512, 512, 512);
    mgemm_k<0, true, true, false, false><<<dim3(64, 4, 1), 256, 0, stream>>>(p);
    p = mk(augNA, wmuT, mu_b, ws + F_NAM, HBT, 512, 512, 512, 512, 512);
    mgemm_k<0, true, true, false, false><<<dim3(64, 4, 1), 256, 0, stream>>>(p);
  }

  gmean_k<<<32, 256, 0, stream>>>(ws + F_NNEW, idxN, ws + O_ANEW);
  gmean_k<<<32, 256, 0, stream>>>(ws + F_MU,   idxA, ws + O_NNEG);
  dist_k<<<32, 256, 0, stream>>>(ws + O_ANEW, ws + O_NNEG, accum);

  xout_k<<<32768, 256, 0, stream>>>(h, ws + F_NNEW, ws + F_VAR, ws + F_MU, ws + F_NAM,
                                    out + OO_XOUT);
  vfeat_k<<<dim3(8, 16, 64), 256, 0, stream>>>(h, out + OO_VFEAT);
  fin_k<<<1, 1, 0, stream>>>(accum, out);
}